// Round 1
// baseline (1397.764 us; speedup 1.0000x reference)
//
#include <hip/hip_runtime.h>

#define NB 16      // B
#define NN 1024    // N
#define ND 16      // D
#define NCI 128    // CI
#define NCO 128    // CO
#define BN_ROWS (NB*NN)
#define MAXDEG 128

// ---------------- BatchNorm ----------------
__global__ void k_bnstats(const float* __restrict__ x, float* __restrict__ stats) {
    int t = threadIdx.x;
    int ci = t & 127;
    int h = t >> 7;
    int row0 = blockIdx.x * 256;
    float s = 0.f, sq = 0.f;
    for (int r = row0 + h; r < row0 + 256; r += 2) {
        float v = x[(size_t)r * NCI + ci];
        s += v; sq += v * v;
    }
    __shared__ float ls[128], lq[128];
    if (h == 1) { ls[ci] = s; lq[ci] = sq; }
    __syncthreads();
    if (h == 0) {
        atomicAdd(&stats[ci], s + ls[ci]);
        atomicAdd(&stats[128 + ci], sq + lq[ci]);
    }
}

__global__ void k_bnfin(const float* __restrict__ stats, const float* __restrict__ gamma,
                        const float* __restrict__ beta, float* __restrict__ ss) {
    int ci = threadIdx.x;
    float mu = stats[ci] * (1.f / BN_ROWS);
    float var = stats[128 + ci] * (1.f / BN_ROWS) - mu * mu;
    float sc = gamma[ci] * rsqrtf(var + 1e-5f);
    ss[ci] = sc;
    ss[128 + ci] = beta[ci] - mu * sc;
}

__global__ void k_xn(const float* __restrict__ x, const float* __restrict__ ss,
                     float* __restrict__ xn) {
    int i = blockIdx.x * 256 + threadIdx.x;   // < B*N*CI
    int ci = i & 127;
    xn[i] = x[i] * ss[ci] + ss[128 + ci];
}

__global__ void k_xnmean(const float* __restrict__ xn, float* __restrict__ xm) {
    int b = blockIdx.x;
    int t = threadIdx.x;
    int ci = t & 127, h = t >> 7;
    float s = 0.f;
    for (int n = h; n < NN; n += 2) s += xn[((size_t)b * NN + n) * NCI + ci];
    __shared__ float ls[128];
    if (h == 1) ls[ci] = s;
    __syncthreads();
    if (h == 0) xm[b * NCI + ci] = (s + ls[ci]) * (1.f / NN);
}

// ---------------- adjacency: degree + neighbor lists ----------------
__global__ void k_nbr(const float* __restrict__ adj, float* __restrict__ dis,
                      int* __restrict__ nbr_idx, int* __restrict__ nbr_cnt) {
    int bm = blockIdx.x;              // b*N + m
    int m = bm & (NN - 1);
    const float* row = adj + (size_t)bm * NN;
    __shared__ int cnt;
    __shared__ int idx[MAXDEG];
    if (threadIdx.x == 0) { cnt = 1; idx[0] = m; }   // forced self-loop
    __syncthreads();
    for (int n = threadIdx.x; n < NN; n += 256) {
        if (n != m && row[n] > 0.5f) {
            int p = atomicAdd(&cnt, 1);
            if (p < MAXDEG) idx[p] = n;
        }
    }
    __syncthreads();
    int c = min(cnt, MAXDEG);
    if (threadIdx.x == 0) {
        nbr_cnt[bm] = c;
        dis[bm] = rsqrtf((float)c);   // rowsum = deg + 1 = cnt (adj is 0/1), >= 1
    }
    for (int k = threadIdx.x; k < c; k += 256) nbr_idx[(size_t)bm * MAXDEG + k] = idx[k];
}

// ---------------- y = a_norm @ xn  (sparse gather) ----------------
__global__ void k_y(const float* __restrict__ xn, const float* __restrict__ dis,
                    const int* __restrict__ nbr_idx, const int* __restrict__ nbr_cnt,
                    float* __restrict__ y) {
    int bm = blockIdx.x;
    int b = bm >> 10;
    int t = threadIdx.x;  // 128
    __shared__ float sw[MAXDEG];
    __shared__ int sIdx[MAXDEG];
    int cnt = nbr_cnt[bm];
    float dm = dis[bm];
    for (int k = t; k < cnt; k += 128) {
        int n = nbr_idx[(size_t)bm * MAXDEG + k];
        sIdx[k] = n;
        sw[k] = dm * dis[(b << 10) + n];
    }
    __syncthreads();
    float acc = 0.f;
    for (int k = 0; k < cnt; ++k)
        acc = fmaf(sw[k], xn[((size_t)(b << 10) + sIdx[k]) * NCI + t], acc);
    y[(size_t)bm * NCI + t] = acc;
}

// ---------------- u = y @ W[d] + bias[d]  (fp32 tiled GEMM) ----------------
__global__ __launch_bounds__(256) void k_ugemm(const float* __restrict__ y,
                                               const float* __restrict__ Wt,
                                               const float* __restrict__ bias,
                                               float* __restrict__ u) {
    int d = blockIdx.y;
    int row0 = blockIdx.x * 64;
    int t = threadIdx.x;
    int tCol = (t & 31) * 4;   // 0..124
    int tRow = (t >> 5) * 8;   // 0..56
    __shared__ float sA[64][128];   // 32KB
    __shared__ float sW[16][128];   //  8KB
    #pragma unroll
    for (int j = 0; j < 32; ++j) {
        int flat = j * 256 + t;   // 8192 = 64*128
        sA[flat >> 7][flat & 127] = y[(size_t)(row0 + (flat >> 7)) * NCI + (flat & 127)];
    }
    float acc[8][4];
    float4 bv = *(const float4*)&bias[d * NCO + tCol];
    #pragma unroll
    for (int i = 0; i < 8; ++i) { acc[i][0]=bv.x; acc[i][1]=bv.y; acc[i][2]=bv.z; acc[i][3]=bv.w; }
    const float* Wd = Wt + (size_t)d * NCI * NCO;
    for (int kk = 0; kk < 128; kk += 16) {
        __syncthreads();
        #pragma unroll
        for (int j = 0; j < 8; ++j) {
            int flat = j * 256 + t;   // 2048 = 16*128
            sW[flat >> 7][flat & 127] = Wd[(size_t)(kk + (flat >> 7)) * NCO + (flat & 127)];
        }
        __syncthreads();
        #pragma unroll
        for (int k = 0; k < 16; ++k) {
            float4 wv = *(const float4*)&sW[k][tCol];
            #pragma unroll
            for (int i = 0; i < 8; ++i) {
                float a = sA[tRow + i][kk + k];
                acc[i][0] = fmaf(a, wv.x, acc[i][0]);
                acc[i][1] = fmaf(a, wv.y, acc[i][1]);
                acc[i][2] = fmaf(a, wv.z, acc[i][2]);
                acc[i][3] = fmaf(a, wv.w, acc[i][3]);
            }
        }
    }
    #pragma unroll
    for (int i = 0; i < 8; ++i) {
        float4 v = make_float4(acc[i][0], acc[i][1], acc[i][2], acc[i][3]);
        *(float4*)&u[((size_t)(row0 + tRow + i) * ND + d) * NCO + tCol] = v;
    }
}

// ---------------- routing ----------------
__global__ void k_sparsemax(const float* __restrict__ blog, float* __restrict__ c) {
    int i = blockIdx.x * 256 + threadIdx.x;   // (b*N+n)
    float z[16], zs[16];
    const float* src = blog + (size_t)i * ND;
    #pragma unroll
    for (int d = 0; d < 16; ++d) { z[d] = src[d]; zs[d] = z[d]; }
    // selection sort descending (fully unrolled, registers)
    #pragma unroll
    for (int a = 0; a < 16; ++a) {
        #pragma unroll
        for (int b2 = a + 1; b2 < 16; ++b2) {
            float hi = fmaxf(zs[a], zs[b2]);
            float lo = fminf(zs[a], zs[b2]);
            zs[a] = hi; zs[b2] = lo;
        }
    }
    float cs = 0.f, tausum = 0.f;
    int kz = 1;
    #pragma unroll
    for (int k = 1; k <= 16; ++k) {
        cs += zs[k - 1];
        if (1.f + (float)k * zs[k - 1] > cs) { kz = k; tausum = cs; }
    }
    float tau = (tausum - 1.f) / (float)kz;
    float* dst = c + (size_t)i * ND;
    #pragma unroll
    for (int d = 0; d < 16; ++d) dst[d] = fmaxf(z[d] - tau, 0.f);
}

// s[b,d,o] = sum_n c[b,n,d] * u[b,n,d,o]; final: += xm, elementwise squash -> out
__global__ void k_s(const float* __restrict__ u, const float* __restrict__ c,
                    const float* __restrict__ xm, float* __restrict__ sbuf,
                    float* __restrict__ outv, int final_flag) {
    int bd = blockIdx.x;          // b*16+d
    int b = bd >> 4, d = bd & 15;
    int t = threadIdx.x;
    int o = t & 127, h = t >> 7;
    float acc = 0.f;
    for (int n = h; n < NN; n += 2) {
        float cv = c[((size_t)(b << 10) + n) * ND + d];
        if (cv == 0.f) continue;   // wave-uniform skip: saves the u read
        acc = fmaf(cv, u[(((size_t)(b << 10) + n) * ND + d) * NCO + o], acc);
    }
    __shared__ float ls[128];
    if (h == 1) ls[o] = acc;
    __syncthreads();
    if (h == 0) {
        acc += ls[o];
        if (!final_flag) {
            sbuf[(size_t)bd * NCO + o] = acc;
        } else {
            float sv = acc + xm[b * NCO + o];
            float sq = sv * sv;
            outv[(size_t)bd * NCO + o] = (sq / (1.f + sq)) * sv * rsqrtf(sq + 1e-8f);
        }
    }
}

__global__ void k_squash(const float* __restrict__ sbuf, float* __restrict__ vbuf) {
    int bd = blockIdx.x;
    int t = threadIdx.x;   // 128
    float sv = sbuf[(size_t)bd * NCO + t];
    float sq = sv * sv;
    #pragma unroll
    for (int m = 1; m < 64; m <<= 1) sq += __shfl_xor(sq, m);
    __shared__ float ls[2];
    if ((t & 63) == 0) ls[t >> 6] = sq;
    __syncthreads();
    float tot = ls[0] + ls[1];
    vbuf[(size_t)bd * NCO + t] = (tot / (1.f + tot)) * sv * rsqrtf(tot + 1e-8f);
}

// b[b,n,d] += sum_o u[b,n,d,o] * v[b,d,o]
__global__ void k_bupd(const float* __restrict__ u, const float* __restrict__ vbuf,
                       float* __restrict__ blog) {
    int bn = blockIdx.x;
    int b = bn >> 10;
    int t = threadIdx.x;     // 256 = d*16 + i
    int d = t >> 4, i = t & 15;
    __shared__ float sv[ND * NCO];
    for (int j = t; j < ND * NCO; j += 256) sv[j] = vbuf[(size_t)b * ND * NCO + j];
    __syncthreads();
    const float* ur = u + (size_t)bn * ND * NCO;
    float acc = 0.f;
    #pragma unroll
    for (int j = 0; j < 8; ++j) {
        int o = i + 16 * j;
        acc = fmaf(ur[d * NCO + o], sv[d * NCO + o], acc);
    }
    #pragma unroll
    for (int m = 8; m; m >>= 1) acc += __shfl_down(acc, m);
    if (i == 0) blog[(size_t)bn * ND + d] += acc;
}

// ---------------- adj_out ----------------
// t[b,d,m] = sum_n c[b,n,d] * adj[b,n,m]
__global__ void k_t(const float* __restrict__ adj, const float* __restrict__ c,
                    float* __restrict__ tbuf) {
    int b = blockIdx.x >> 2;
    int mc = blockIdx.x & 3;
    int m = mc * 256 + threadIdx.x;
    float acc[16] = {};
    __shared__ float sc[64][16];
    for (int n0 = 0; n0 < NN; n0 += 64) {
        __syncthreads();
        for (int j = threadIdx.x; j < 64 * 16; j += 256)
            sc[j >> 4][j & 15] = c[((size_t)(b << 10) + n0 + (j >> 4)) * ND + (j & 15)];
        __syncthreads();
        for (int nn = 0; nn < 64; ++nn) {
            float av = adj[((size_t)(b << 10) + n0 + nn) * NN + m];
            if (av != 0.f) {
                #pragma unroll
                for (int d2 = 0; d2 < 16; ++d2) acc[d2] = fmaf(av, sc[nn][d2], acc[d2]);
            }
        }
    }
    #pragma unroll
    for (int d2 = 0; d2 < 16; ++d2) tbuf[((size_t)b * ND + d2) * NN + m] = acc[d2];
}

// adj_out[b,d,e] = sum_m t[b,d,m] * c[b,m,e]
__global__ void k_adjout(const float* __restrict__ tbuf, const float* __restrict__ c,
                         float* __restrict__ out) {
    int b = blockIdx.x;
    int t = threadIdx.x;   // 256 = d*16+e
    int d = t >> 4, e = t & 15;
    float acc = 0.f;
    for (int m = 0; m < NN; ++m)
        acc = fmaf(tbuf[((size_t)b * ND + d) * NN + m], c[((size_t)(b << 10) + m) * ND + e], acc);
    out[((size_t)b * ND + d) * ND + e] = acc;
}

extern "C" void kernel_launch(void* const* d_in, const int* in_sizes, int n_in,
                              void* d_out, int out_size, void* d_ws, size_t ws_size,
                              hipStream_t stream) {
    const float* x     = (const float*)d_in[0];
    const float* adj   = (const float*)d_in[1];
    const float* gamma = (const float*)d_in[2];
    const float* beta  = (const float*)d_in[3];
    const float* W     = (const float*)d_in[4];
    const float* bias  = (const float*)d_in[5];
    float* out = (float*)d_out;

    char* wptr = (char*)d_ws;
    size_t used = 0;
    auto alloc = [&](size_t nbytes) -> void* {
        void* p = wptr + used;
        used += (nbytes + 255) & ~(size_t)255;
        return p;
    };
    float* stats   = (float*)alloc(256 * 4);
    float* ss      = (float*)alloc(256 * 4);
    float* xm      = (float*)alloc((size_t)NB * NCI * 4);
    float* dis     = (float*)alloc((size_t)NB * NN * 4);
    int*   nbr_cnt = (int*)alloc((size_t)NB * NN * 4);
    float* xn      = (float*)alloc((size_t)NB * NN * NCI * 4);
    float* y       = (float*)alloc((size_t)NB * NN * NCI * 4);
    float* u       = (float*)alloc((size_t)NB * NN * ND * NCO * 4);
    float* blog    = (float*)alloc((size_t)NB * NN * ND * 4);
    float* c       = (float*)alloc((size_t)NB * NN * ND * 4);
    float* sbuf    = (float*)alloc((size_t)NB * ND * NCO * 4);
    float* vbuf    = (float*)alloc((size_t)NB * ND * NCO * 4);
    float* tbuf    = (float*)alloc((size_t)NB * ND * NN * 4);
    int*   nbr_idx = (int*)alloc((size_t)NB * NN * MAXDEG * 4);
    if (used > ws_size) return;  // ws too small: leave output (will fail loudly, not corrupt)

    hipMemsetAsync(stats, 0, 256 * 4, stream);
    hipMemsetAsync(blog, 0, (size_t)NB * NN * ND * 4, stream);

    k_bnstats<<<64, 256, 0, stream>>>(x, stats);
    k_bnfin<<<1, 128, 0, stream>>>(stats, gamma, beta, ss);
    k_xn<<<(NB * NN * NCI) / 256, 256, 0, stream>>>(x, ss, xn);
    k_xnmean<<<NB, 256, 0, stream>>>(xn, xm);
    k_nbr<<<NB * NN, 256, 0, stream>>>(adj, dis, nbr_idx, nbr_cnt);
    k_y<<<NB * NN, 128, 0, stream>>>(xn, dis, nbr_idx, nbr_cnt, y);
    k_ugemm<<<dim3(BN_ROWS / 64, ND), 256, 0, stream>>>(y, W, bias, u);

    for (int it = 0; it < 2; ++it) {
        k_sparsemax<<<(NB * NN) / 256, 256, 0, stream>>>(blog, c);
        k_s<<<NB * ND, 256, 0, stream>>>(u, c, xm, sbuf, out, 0);
        k_squash<<<NB * ND, 128, 0, stream>>>(sbuf, vbuf);
        k_bupd<<<NB * NN, 256, 0, stream>>>(u, vbuf, blog);
    }
    k_sparsemax<<<(NB * NN) / 256, 256, 0, stream>>>(blog, c);
    k_s<<<NB * ND, 256, 0, stream>>>(u, c, xm, sbuf, out, 1);

    k_t<<<NB * 4, 256, 0, stream>>>(adj, c, tbuf);
    k_adjout<<<NB, 256, 0, stream>>>(tbuf, c, out + (size_t)NB * ND * NCO);
}

// Round 2
// 336.070 us; speedup vs baseline: 4.1591x; 4.1591x over previous
//
#include <hip/hip_runtime.h>

#define NB 16      // B
#define NN 1024    // N
#define ND 16      // D
#define NCI 128    // CI
#define NCO 128    // CO
#define BN_ROWS (NB*NN)
#define MAXDEG 128

// ---------------- BatchNorm ----------------
__global__ void k_bnstats(const float* __restrict__ x, float* __restrict__ stats) {
    int t = threadIdx.x;
    int ci = t & 127;
    int h = t >> 7;
    int row0 = blockIdx.x * 256;
    float s = 0.f, sq = 0.f;
    for (int r = row0 + h; r < row0 + 256; r += 2) {
        float v = x[(size_t)r * NCI + ci];
        s += v; sq += v * v;
    }
    __shared__ float ls[128], lq[128];
    if (h == 1) { ls[ci] = s; lq[ci] = sq; }
    __syncthreads();
    if (h == 0) {
        atomicAdd(&stats[ci], s + ls[ci]);
        atomicAdd(&stats[128 + ci], sq + lq[ci]);
    }
}

__global__ void k_bnfin(const float* __restrict__ stats, const float* __restrict__ gamma,
                        const float* __restrict__ beta, float* __restrict__ ss) {
    int ci = threadIdx.x;
    float mu = stats[ci] * (1.f / BN_ROWS);
    float var = stats[128 + ci] * (1.f / BN_ROWS) - mu * mu;
    float sc = gamma[ci] * rsqrtf(var + 1e-5f);
    ss[ci] = sc;
    ss[128 + ci] = beta[ci] - mu * sc;
}

__global__ void k_xn(const float* __restrict__ x, const float* __restrict__ ss,
                     float* __restrict__ xn) {
    int i = blockIdx.x * 256 + threadIdx.x;   // < B*N*CI
    int ci = i & 127;
    xn[i] = x[i] * ss[ci] + ss[128 + ci];
}

__global__ void k_xnmean(const float* __restrict__ xn, float* __restrict__ xm) {
    int b = blockIdx.x;
    int t = threadIdx.x;
    int ci = t & 127, h = t >> 7;
    float s = 0.f;
    for (int n = h; n < NN; n += 2) s += xn[((size_t)b * NN + n) * NCI + ci];
    __shared__ float ls[128];
    if (h == 1) ls[ci] = s;
    __syncthreads();
    if (h == 0) xm[b * NCI + ci] = (s + ls[ci]) * (1.f / NN);
}

// ---------------- adjacency: degree + neighbor lists + self-diag flag ----------------
__global__ void k_nbr(const float* __restrict__ adj, float* __restrict__ dis,
                      int* __restrict__ nbr_idx, int* __restrict__ nbr_cnt,
                      float* __restrict__ selfd) {
    int bm = blockIdx.x;              // b*N + m
    int m = bm & (NN - 1);
    const float* row = adj + (size_t)bm * NN;
    __shared__ int cnt;
    __shared__ int idx[MAXDEG];
    if (threadIdx.x == 0) { cnt = 1; idx[0] = m; }   // forced self-loop
    __syncthreads();
    for (int n = threadIdx.x; n < NN; n += 256) {
        float av = row[n];
        if (n == m) {
            selfd[bm] = (av > 0.5f) ? 1.f : 0.f;   // actual diag of raw adj
        } else if (av > 0.5f) {
            int p = atomicAdd(&cnt, 1);
            if (p < MAXDEG) idx[p] = n;
        }
    }
    __syncthreads();
    int c = min(cnt, MAXDEG);
    if (threadIdx.x == 0) {
        nbr_cnt[bm] = c;
        dis[bm] = rsqrtf((float)c);   // rowsum = deg + 1 = cnt (adj is 0/1), >= 1
    }
    for (int k = threadIdx.x; k < c; k += 256) nbr_idx[(size_t)bm * MAXDEG + k] = idx[k];
}

// ---------------- y = a_norm @ xn  (sparse gather) ----------------
__global__ void k_y(const float* __restrict__ xn, const float* __restrict__ dis,
                    const int* __restrict__ nbr_idx, const int* __restrict__ nbr_cnt,
                    float* __restrict__ y) {
    int bm = blockIdx.x;
    int b = bm >> 10;
    int t = threadIdx.x;  // 128
    __shared__ float sw[MAXDEG];
    __shared__ int sIdx[MAXDEG];
    int cnt = nbr_cnt[bm];
    float dm = dis[bm];
    for (int k = t; k < cnt; k += 128) {
        int n = nbr_idx[(size_t)bm * MAXDEG + k];
        sIdx[k] = n;
        sw[k] = dm * dis[(b << 10) + n];
    }
    __syncthreads();
    float acc = 0.f;
    for (int k = 0; k < cnt; ++k)
        acc = fmaf(sw[k], xn[((size_t)(b << 10) + sIdx[k]) * NCI + t], acc);
    y[(size_t)bm * NCI + t] = acc;
}

// ---------------- routing ----------------
__global__ void k_sparsemax(const float* __restrict__ blog, float* __restrict__ c) {
    int i = blockIdx.x * 256 + threadIdx.x;   // (b*N+n)
    float z[16], zs[16];
    const float* src = blog + (size_t)i * ND;
    #pragma unroll
    for (int d = 0; d < 16; ++d) { z[d] = src[d]; zs[d] = z[d]; }
    #pragma unroll
    for (int a = 0; a < 16; ++a) {
        #pragma unroll
        for (int b2 = a + 1; b2 < 16; ++b2) {
            float hi = fmaxf(zs[a], zs[b2]);
            float lo = fminf(zs[a], zs[b2]);
            zs[a] = hi; zs[b2] = lo;
        }
    }
    float cs = 0.f, tausum = 0.f;
    int kz = 1;
    #pragma unroll
    for (int k = 1; k <= 16; ++k) {
        cs += zs[k - 1];
        if (1.f + (float)k * zs[k - 1] > cs) { kz = k; tausum = cs; }
    }
    float tau = (tausum - 1.f) / (float)kz;
    float* dst = c + (size_t)i * ND;
    #pragma unroll
    for (int d = 0; d < 16; ++d) dst[d] = fmaxf(z[d] - tau, 0.f);
}

// partial g[b,ch,d,i] = sum_{n in chunk} c[b,n,d] * y[b,n,i]; also partial csum
__global__ void k_g(const float* __restrict__ y, const float* __restrict__ c,
                    float* __restrict__ pg, float* __restrict__ pcs) {
    int blk = blockIdx.x; int b = blk >> 4, ch = blk & 15;
    int t = threadIdx.x;  // 128
    __shared__ float sc[64][16];
    int n0 = ch * 64;
    for (int j = t; j < 64 * 16; j += 128)
        sc[j >> 4][j & 15] = c[(((size_t)b << 10) + n0 + (j >> 4)) * ND + (j & 15)];
    __syncthreads();
    float acc[16] = {};
    const float* yb = y + (((size_t)b << 10) + n0) * NCI + t;
    for (int n = 0; n < 64; ++n) {
        float yv = yb[(size_t)n * NCI];
        #pragma unroll
        for (int d = 0; d < 16; ++d) acc[d] = fmaf(sc[n][d], yv, acc[d]);
    }
    #pragma unroll
    for (int d = 0; d < 16; ++d)
        pg[(((size_t)b * 16 + ch) * 16 + d) * NCI + t] = acc[d];
    if (t < 16) {
        float cs = 0.f;
        for (int n = 0; n < 64; ++n) cs += sc[n][t];
        pcs[(b * 16 + ch) * 16 + t] = cs;
    }
}

// s[b,d,o] = g[b,d,:].W[d,:,o] + csum*bias[d,o] (+xm, squash variants)
__global__ void k_sv(const float* __restrict__ pg, const float* __restrict__ pcs,
                     const float* __restrict__ W, const float* __restrict__ bias,
                     const float* __restrict__ xm, float* __restrict__ vbuf,
                     float* __restrict__ outv, int final_flag) {
    int bd = blockIdx.x; int b = bd >> 4, d = bd & 15;
    int t = threadIdx.x;  // 128
    __shared__ float gl[128];
    __shared__ float csum_s;
    float gsum = 0.f;
    #pragma unroll
    for (int ch = 0; ch < 16; ++ch)
        gsum += pg[(((size_t)b * 16 + ch) * 16 + d) * NCI + t];
    gl[t] = gsum;
    if (t == 0) {
        float cs = 0.f;
        #pragma unroll
        for (int ch = 0; ch < 16; ++ch) cs += pcs[(b * 16 + ch) * 16 + d];
        csum_s = cs;
    }
    __syncthreads();
    float acc = csum_s * bias[d * NCO + t];
    const float* Wd = W + (size_t)d * NCI * NCO;
    #pragma unroll 4
    for (int i = 0; i < 128; ++i) acc = fmaf(gl[i], Wd[(size_t)i * NCO + t], acc);
    if (final_flag) {
        float sv = acc + xm[b * NCO + t];
        float sq = sv * sv;
        outv[(size_t)bd * NCO + t] = (sq / (1.f + sq)) * sv * rsqrtf(sq + 1e-8f);
    } else {
        float sq = acc * acc;
        #pragma unroll
        for (int m = 1; m < 64; m <<= 1) sq += __shfl_xor(sq, m);
        __shared__ float l2[2];
        if ((t & 63) == 0) l2[t >> 6] = sq;
        __syncthreads();
        float tot = l2[0] + l2[1];
        vbuf[(size_t)bd * NCO + t] = (tot / (1.f + tot)) * acc * rsqrtf(tot + 1e-8f);
    }
}

// h[b,d,i] = sum_o W[d,i,o]*v[b,d,o]; hbb[b,d] = dot(bias[d], v[b,d])
__global__ void k_h(const float* __restrict__ W, const float* __restrict__ bias,
                    const float* __restrict__ vbuf, float* __restrict__ hbuf,
                    float* __restrict__ hbb) {
    int bd = blockIdx.x; int d = bd & 15;
    int t = threadIdx.x;  // 128
    __shared__ float sv[128];
    sv[t] = vbuf[(size_t)bd * NCO + t];
    __syncthreads();
    const float* Wr = W + ((size_t)d * NCI + t) * NCO;
    float acc = 0.f;
    #pragma unroll 8
    for (int o = 0; o < 128; o += 4) {
        float4 w4 = *(const float4*)&Wr[o];
        acc = fmaf(w4.x, sv[o], acc);
        acc = fmaf(w4.y, sv[o + 1], acc);
        acc = fmaf(w4.z, sv[o + 2], acc);
        acc = fmaf(w4.w, sv[o + 3], acc);
    }
    hbuf[(size_t)bd * NCI + t] = acc;
    float pb = bias[d * NCO + t] * sv[t];
    #pragma unroll
    for (int m = 1; m < 64; m <<= 1) pb += __shfl_xor(pb, m);
    __shared__ float l2[2];
    if ((t & 63) == 0) l2[t >> 6] = pb;
    __syncthreads();
    if (t == 0) hbb[bd] = l2[0] + l2[1];
}

// blog[b,n,d] += y[b,n,:].h[b,d,:] + hbb[b,d]
__global__ __launch_bounds__(256) void k_bupd(const float* __restrict__ y,
                                              const float* __restrict__ hbuf,
                                              const float* __restrict__ hbb,
                                              float* __restrict__ blog) {
    int blk = blockIdx.x; int b = blk >> 4, ch = blk & 15;
    int t = threadIdx.x;  // 256
    int nsub = t >> 4, d = t & 15;
    __shared__ float sh[16][132];
    __shared__ float sy[64][132];
    __shared__ float shb[16];
    for (int j = t; j < 16 * 128; j += 256)
        sh[j >> 7][j & 127] = hbuf[(size_t)b * 16 * NCI + j];
    if (t < 16) shb[t] = hbb[b * 16 + t];
    int n0 = ch * 64;
    for (int j = t; j < 64 * 128; j += 256)
        sy[j >> 7][j & 127] = y[(((size_t)b << 10) + n0) * NCI + j];
    __syncthreads();
    for (int nn = nsub; nn < 64; nn += 16) {
        float acc = 0.f;
        #pragma unroll 8
        for (int i4 = 0; i4 < 128; i4 += 4) {
            float4 a = *(const float4*)&sy[nn][i4];
            float4 h4 = *(const float4*)&sh[d][i4];
            acc = fmaf(a.x, h4.x, acc);
            acc = fmaf(a.y, h4.y, acc);
            acc = fmaf(a.z, h4.z, acc);
            acc = fmaf(a.w, h4.w, acc);
        }
        size_t idx = (((size_t)b << 10) + n0 + nn) * ND + d;
        blog[idx] += acc + shb[d];
    }
}

// ---------------- adj_out via neighbor lists ----------------
// t[b,d,m] = sum_{n in N(m)} c[b,n,d]  (correct forced self-loop if diag was 0)
__global__ void k_t2(const float* __restrict__ c, const int* __restrict__ nbr_idx,
                     const int* __restrict__ nbr_cnt, const float* __restrict__ selfd,
                     float* __restrict__ tbuf) {
    int bm = blockIdx.x; int b = bm >> 10, m = bm & 1023;
    int t = threadIdx.x;  // 64
    int nsub = t >> 4, d = t & 15;
    int cnt = nbr_cnt[bm];
    float acc = 0.f;
    for (int k = nsub; k < cnt; k += 4) {
        int n = nbr_idx[(size_t)bm * MAXDEG + k];
        acc += c[(((size_t)b << 10) + n) * ND + d];
    }
    acc += __shfl_xor(acc, 16);
    acc += __shfl_xor(acc, 32);
    if (t < 16) {
        if (selfd[bm] == 0.f) acc -= c[(size_t)bm * ND + d];
        tbuf[((size_t)b * 16 + d) * NN + m] = acc;
    }
}

// adj_out[b,d,e] = sum_m t[b,d,m] * c[b,m,e]
__global__ void k_adjout(const float* __restrict__ tbuf, const float* __restrict__ c,
                         float* __restrict__ out) {
    int bd = blockIdx.x; int b = bd >> 4;
    int t = threadIdx.x;  // 128
    int msub = t >> 4, e = t & 15;
    const float* tr = tbuf + (size_t)bd * NN;
    float acc = 0.f;
    for (int m = msub; m < NN; m += 8)
        acc = fmaf(tr[m], c[(((size_t)b << 10) + m) * ND + e], acc);
    acc += __shfl_xor(acc, 16);
    acc += __shfl_xor(acc, 32);
    __shared__ float l2[2][16];
    if ((t & 63) < 16) l2[t >> 6][e] = acc;
    __syncthreads();
    if (t < 16) out[(size_t)bd * ND + t] = l2[0][t] + l2[1][t];
}

extern "C" void kernel_launch(void* const* d_in, const int* in_sizes, int n_in,
                              void* d_out, int out_size, void* d_ws, size_t ws_size,
                              hipStream_t stream) {
    const float* x     = (const float*)d_in[0];
    const float* adj   = (const float*)d_in[1];
    const float* gamma = (const float*)d_in[2];
    const float* beta  = (const float*)d_in[3];
    const float* W     = (const float*)d_in[4];
    const float* bias  = (const float*)d_in[5];
    float* out = (float*)d_out;

    char* wptr = (char*)d_ws;
    size_t used = 0;
    auto alloc = [&](size_t nbytes) -> void* {
        void* p = wptr + used;
        used += (nbytes + 255) & ~(size_t)255;
        return p;
    };
    float* stats   = (float*)alloc(256 * 4);
    float* ss      = (float*)alloc(256 * 4);
    float* xm      = (float*)alloc((size_t)NB * NCI * 4);
    float* dis     = (float*)alloc((size_t)NB * NN * 4);
    float* selfd   = (float*)alloc((size_t)NB * NN * 4);
    int*   nbr_cnt = (int*)alloc((size_t)NB * NN * 4);
    float* xn      = (float*)alloc((size_t)NB * NN * NCI * 4);
    float* y       = (float*)alloc((size_t)NB * NN * NCI * 4);
    float* blog    = (float*)alloc((size_t)NB * NN * ND * 4);
    float* c       = (float*)alloc((size_t)NB * NN * ND * 4);
    float* pg      = (float*)alloc((size_t)NB * 16 * ND * NCI * 4);
    float* pcs     = (float*)alloc((size_t)NB * 16 * ND * 4);
    float* vbuf    = (float*)alloc((size_t)NB * ND * NCO * 4);
    float* hbuf    = (float*)alloc((size_t)NB * ND * NCI * 4);
    float* hbb     = (float*)alloc((size_t)NB * ND * 4);
    float* tbuf    = (float*)alloc((size_t)NB * ND * NN * 4);
    int*   nbr_idx = (int*)alloc((size_t)NB * NN * MAXDEG * 4);
    if (used > ws_size) return;

    hipMemsetAsync(stats, 0, 256 * 4, stream);
    hipMemsetAsync(blog, 0, (size_t)NB * NN * ND * 4, stream);

    k_bnstats<<<64, 256, 0, stream>>>(x, stats);
    k_bnfin<<<1, 128, 0, stream>>>(stats, gamma, beta, ss);
    k_xn<<<(NB * NN * NCI) / 256, 256, 0, stream>>>(x, ss, xn);
    k_xnmean<<<NB, 256, 0, stream>>>(xn, xm);
    k_nbr<<<NB * NN, 256, 0, stream>>>(adj, dis, nbr_idx, nbr_cnt, selfd);
    k_y<<<NB * NN, 128, 0, stream>>>(xn, dis, nbr_idx, nbr_cnt, y);

    for (int it = 0; it < 2; ++it) {
        k_sparsemax<<<(NB * NN) / 256, 256, 0, stream>>>(blog, c);
        k_g<<<NB * 16, 128, 0, stream>>>(y, c, pg, pcs);
        k_sv<<<NB * ND, 128, 0, stream>>>(pg, pcs, W, bias, xm, vbuf, out, 0);
        k_h<<<NB * ND, 128, 0, stream>>>(W, bias, vbuf, hbuf, hbb);
        k_bupd<<<NB * 16, 256, 0, stream>>>(y, hbuf, hbb, blog);
    }
    k_sparsemax<<<(NB * NN) / 256, 256, 0, stream>>>(blog, c);
    k_g<<<NB * 16, 128, 0, stream>>>(y, c, pg, pcs);
    k_sv<<<NB * ND, 128, 0, stream>>>(pg, pcs, W, bias, xm, vbuf, out, 1);

    k_t2<<<NB * NN, 64, 0, stream>>>(c, nbr_idx, nbr_cnt, selfd, tbuf);
    k_adjout<<<NB * ND, 128, 0, stream>>>(tbuf, c, out + (size_t)NB * ND * NCO);
}

// Round 3
// 210.838 us; speedup vs baseline: 6.6296x; 1.5940x over previous
//
#include <hip/hip_runtime.h>

#define NB 16      // B
#define NN 1024    // N
#define ND 16      // D
#define NCI 128    // CI
#define NCO 128    // CO
#define BN_ROWS (NB*NN)
#define MAXDEG 128

// ---------------- BatchNorm stats + per-b sums ----------------
__global__ void k_bnstats(const float* __restrict__ x, float* __restrict__ stats,
                          float* __restrict__ xsum) {
    int t = threadIdx.x;
    int ci = t & 127;
    int h = t >> 7;
    int row0 = blockIdx.x * 256;
    float s = 0.f, sq = 0.f;
    for (int r = row0 + h; r < row0 + 256; r += 2) {
        float v = x[(size_t)r * NCI + ci];
        s += v; sq += v * v;
    }
    __shared__ float ls[128], lq[128];
    if (h == 1) { ls[ci] = s; lq[ci] = sq; }
    __syncthreads();
    if (h == 0) {
        float ts = s + ls[ci];
        atomicAdd(&stats[ci], ts);
        atomicAdd(&stats[128 + ci], sq + lq[ci]);
        atomicAdd(&xsum[(blockIdx.x >> 2) * 128 + ci], ts);  // per-b partial
    }
}

// ss (scale/shift) + xm[b,:] = sc*mean_n(x) + sh
__global__ void k_bnfin(const float* __restrict__ stats, const float* __restrict__ xsum,
                        const float* __restrict__ gamma, const float* __restrict__ beta,
                        float* __restrict__ ss, float* __restrict__ xm) {
    int ci = threadIdx.x;
    int b = blockIdx.x;
    float mu = stats[ci] * (1.f / BN_ROWS);
    float var = stats[128 + ci] * (1.f / BN_ROWS) - mu * mu;
    float sc = gamma[ci] * rsqrtf(var + 1e-5f);
    float sh = beta[ci] - mu * sc;
    if (b == 0) { ss[ci] = sc; ss[128 + ci] = sh; }
    xm[b * NCI + ci] = xsum[b * NCI + ci] * (1.f / NN) * sc + sh;
}

// ---------------- adjacency: degree + neighbor lists + self-diag flag ----------------
__global__ void k_nbr(const float* __restrict__ adj, float* __restrict__ dis,
                      int* __restrict__ nbr_idx, int* __restrict__ nbr_cnt,
                      float* __restrict__ selfd) {
    int bm = blockIdx.x;              // b*N + m
    int m = bm & (NN - 1);
    const float* row = adj + (size_t)bm * NN;
    __shared__ int cnt;
    __shared__ int idx[MAXDEG];
    if (threadIdx.x == 0) { cnt = 1; idx[0] = m; }   // forced self-loop
    __syncthreads();
    for (int n = threadIdx.x; n < NN; n += 256) {
        float av = row[n];
        if (n == m) {
            selfd[bm] = (av > 0.5f) ? 1.f : 0.f;
        } else if (av > 0.5f) {
            int p = atomicAdd(&cnt, 1);
            if (p < MAXDEG) idx[p] = n;
        }
    }
    __syncthreads();
    int c = min(cnt, MAXDEG);
    if (threadIdx.x == 0) {
        nbr_cnt[bm] = c;
        dis[bm] = rsqrtf((float)c);
    }
    for (int k = threadIdx.x; k < c; k += 256) nbr_idx[(size_t)bm * MAXDEG + k] = idx[k];
}

// ---------------- y = a_norm @ (x*sc+sh)  (sparse gather, affine folded) ----------------
__global__ void k_y(const float* __restrict__ x, const float* __restrict__ ss,
                    const float* __restrict__ dis, const int* __restrict__ nbr_idx,
                    const int* __restrict__ nbr_cnt, float* __restrict__ y) {
    int bm = blockIdx.x;
    int b = bm >> 10;
    int t = threadIdx.x;  // 128
    __shared__ float sw[MAXDEG];
    __shared__ int sIdx[MAXDEG];
    int cnt = nbr_cnt[bm];
    float dm = dis[bm];
    for (int k = t; k < cnt; k += 128) {
        int n = nbr_idx[(size_t)bm * MAXDEG + k];
        sIdx[k] = n;
        sw[k] = dm * dis[(b << 10) + n];
    }
    __syncthreads();
    float acc = 0.f, wsum = 0.f;
    for (int k = 0; k < cnt; ++k) {
        float w = sw[k];
        acc = fmaf(w, x[((size_t)(b << 10) + sIdx[k]) * NCI + t], acc);
        wsum += w;
    }
    y[(size_t)bm * NCI + t] = ss[t] * acc + ss[128 + t] * wsum;
}

// partial row-sums of y (iter-0 g is uniform-c): psum[b,ch,i] = sum_{64 rows} y
__global__ void k_ysum(const float* __restrict__ y, float* __restrict__ psum) {
    int blk = blockIdx.x; int b = blk >> 4, ch = blk & 15;
    int t = threadIdx.x;  // 128
    const float* yb = y + (((size_t)b << 10) + ch * 64) * NCI + t;
    float s = 0.f;
    #pragma unroll 4
    for (int n = 0; n < 64; ++n) s += yb[(size_t)n * NCI];
    psum[((size_t)b * 16 + ch) * NCI + t] = s;
}

// s->v->h fused. mode 0: g from psum (uniform c); mode 1: g from pg/pcs; mode 2: final output
__global__ void k_sv(const float* __restrict__ gsrc, const float* __restrict__ pcs,
                     const float* __restrict__ W, const float* __restrict__ bias,
                     const float* __restrict__ xm, float* __restrict__ hbuf,
                     float* __restrict__ hbb, float* __restrict__ outv, int mode) {
    int bd = blockIdx.x; int b = bd >> 4, d = bd & 15;
    int t = threadIdx.x;  // 128
    __shared__ float gl[128];
    __shared__ float csum_s;
    float g = 0.f;
    if (mode == 0) {
        #pragma unroll
        for (int ch = 0; ch < 16; ++ch) g += gsrc[((size_t)b * 16 + ch) * NCI + t];
        g *= (1.f / 16.f);
        if (t == 0) csum_s = 64.f;
    } else {
        #pragma unroll
        for (int ch = 0; ch < 32; ++ch) g += gsrc[(((size_t)b * 32 + ch) * 16 + d) * NCI + t];
        if (t == 0) {
            float cs = 0.f;
            #pragma unroll
            for (int ch = 0; ch < 16; ++ch) cs += pcs[(b * 16 + ch) * 16 + d];
            csum_s = cs;
        }
    }
    gl[t] = g;
    __syncthreads();
    const float* Wd = W + (size_t)d * NCI * NCO;
    float acc = csum_s * bias[d * NCO + t];
    #pragma unroll 4
    for (int i = 0; i < 128; ++i) acc = fmaf(gl[i], Wd[(size_t)i * NCO + t], acc);
    if (mode == 2) {
        float sv2 = acc + xm[b * NCO + t];
        float sq = sv2 * sv2;
        outv[(size_t)bd * NCO + t] = (sq / (1.f + sq)) * sv2 * rsqrtf(sq + 1e-8f);
        return;
    }
    // squash over o
    float sq = acc * acc;
    #pragma unroll
    for (int m = 1; m < 64; m <<= 1) sq += __shfl_xor(sq, m);
    __shared__ float l2a[2];
    if ((t & 63) == 0) l2a[t >> 6] = sq;
    __syncthreads();
    float tot = l2a[0] + l2a[1];
    float v = (tot / (1.f + tot)) * acc * rsqrtf(tot + 1e-8f);
    __shared__ float svv[128];
    svv[t] = v;
    __syncthreads();
    // h[i] = sum_o W[d,i,o] v[o]; hbb = dot(bias[d], v)
    const float* Wr = W + ((size_t)d * NCI + t) * NCO;
    float hacc = 0.f;
    #pragma unroll 8
    for (int o = 0; o < 128; o += 4) {
        float4 w4 = *(const float4*)&Wr[o];
        hacc = fmaf(w4.x, svv[o], hacc);
        hacc = fmaf(w4.y, svv[o + 1], hacc);
        hacc = fmaf(w4.z, svv[o + 2], hacc);
        hacc = fmaf(w4.w, svv[o + 3], hacc);
    }
    hbuf[(size_t)bd * NCI + t] = hacc;
    float pb = bias[d * NCO + t] * v;
    #pragma unroll
    for (int m = 1; m < 64; m <<= 1) pb += __shfl_xor(pb, m);
    __shared__ float l2b[2];
    if ((t & 63) == 0) l2b[t >> 6] = pb;
    __syncthreads();
    if (t == 0) hbb[bd] = l2b[0] + l2b[1];
}

// fused: blog update + sparsemax + g partials (+ optional global c write)
__global__ __launch_bounds__(256) void k_bgc(const float* __restrict__ y,
        const float* __restrict__ hbuf, const float* __restrict__ hbb,
        float* __restrict__ blog, float* __restrict__ cglob,
        float* __restrict__ pg, float* __restrict__ pcs, int first, int last) {
    int blk = blockIdx.x; int b = blk >> 4, ch = blk & 15;
    int t = threadIdx.x;  // 256
    int n0 = ch * 64;
    __shared__ float sh[16 * 128];
    __shared__ float sy[64 * 128];
    __shared__ float shb[16];
    __shared__ float scd[64][17];
    for (int j = t; j < 16 * 128; j += 256) sh[j] = hbuf[(size_t)b * 16 * NCI + j];
    if (t < 16) shb[t] = hbb[b * 16 + t];
    for (int j = t; j < 64 * 128; j += 256)
        sy[j] = y[(((size_t)b << 10) + n0) * NCI + j];
    __syncthreads();
    int nsub = t >> 4, d = t & 15;
    for (int nn = nsub; nn < 64; nn += 16) {
        float acc = 0.f;
        const float* yr = &sy[nn * 128];
        const float* hr = &sh[d * 128];
        #pragma unroll 8
        for (int i = 0; i < 128; i += 4) {
            float4 a = *(const float4*)&yr[i];
            float4 h4 = *(const float4*)&hr[i];
            acc = fmaf(a.x, h4.x, acc);
            acc = fmaf(a.y, h4.y, acc);
            acc = fmaf(a.z, h4.z, acc);
            acc = fmaf(a.w, h4.w, acc);
        }
        size_t idx = (((size_t)b << 10) + n0 + nn) * ND + d;
        float bnew = acc + shb[d] + (first ? 0.f : blog[idx]);
        if (!last) blog[idx] = bnew;
        scd[nn][d] = bnew;
    }
    __syncthreads();
    if (t < 64) {
        float z[16], zs[16];
        #pragma unroll
        for (int d2 = 0; d2 < 16; ++d2) { z[d2] = scd[t][d2]; zs[d2] = z[d2]; }
        #pragma unroll
        for (int a = 0; a < 16; ++a) {
            #pragma unroll
            for (int b2 = a + 1; b2 < 16; ++b2) {
                float hi = fmaxf(zs[a], zs[b2]);
                float lo = fminf(zs[a], zs[b2]);
                zs[a] = hi; zs[b2] = lo;
            }
        }
        float cs = 0.f, tausum = 0.f;
        int kz = 1;
        #pragma unroll
        for (int k = 1; k <= 16; ++k) {
            cs += zs[k - 1];
            if (1.f + (float)k * zs[k - 1] > cs) { kz = k; tausum = cs; }
        }
        float tau = (tausum - 1.f) / (float)kz;
        #pragma unroll
        for (int d2 = 0; d2 < 16; ++d2) scd[t][d2] = fmaxf(z[d2] - tau, 0.f);
    }
    __syncthreads();
    if (last) {
        for (int j = t; j < 64 * 16; j += 256)
            cglob[(((size_t)b << 10) + n0 + (j >> 4)) * ND + (j & 15)] = scd[j >> 4][j & 15];
    }
    if (t < 16) {
        float cs = 0.f;
        #pragma unroll 4
        for (int nn = 0; nn < 64; ++nn) cs += scd[nn][t];
        pcs[(b * 16 + ch) * 16 + t] = cs;
    }
    // pg partials: 2 half-chunks of 32 rows
    int col = t & 127, h2 = t >> 7;
    float accg[16] = {};
    for (int nn = 0; nn < 32; ++nn) {
        int r = h2 * 32 + nn;
        float yv = sy[r * 128 + col];
        #pragma unroll
        for (int d2 = 0; d2 < 16; ++d2) accg[d2] = fmaf(scd[r][d2], yv, accg[d2]);
    }
    #pragma unroll
    for (int d2 = 0; d2 < 16; ++d2)
        pg[(((size_t)b * 32 + ch * 2 + h2) * 16 + d2) * NCI + col] = accg[d2];
}

// ---------------- adj_out via neighbor lists ----------------
__global__ void k_t2(const float* __restrict__ c, const int* __restrict__ nbr_idx,
                     const int* __restrict__ nbr_cnt, const float* __restrict__ selfd,
                     float* __restrict__ tbuf) {
    int bm = blockIdx.x; int b = bm >> 10, m = bm & 1023;
    int t = threadIdx.x;  // 64
    int nsub = t >> 4, d = t & 15;
    int cnt = nbr_cnt[bm];
    float acc = 0.f;
    for (int k = nsub; k < cnt; k += 4) {
        int n = nbr_idx[(size_t)bm * MAXDEG + k];
        acc += c[(((size_t)b << 10) + n) * ND + d];
    }
    acc += __shfl_xor(acc, 16);
    acc += __shfl_xor(acc, 32);
    if (t < 16) {
        if (selfd[bm] == 0.f) acc -= c[(size_t)bm * ND + d];
        tbuf[((size_t)b * 16 + d) * NN + m] = acc;
    }
}

__global__ void k_adjout(const float* __restrict__ tbuf, const float* __restrict__ c,
                         float* __restrict__ out) {
    int bd = blockIdx.x; int b = bd >> 4;
    int t = threadIdx.x;  // 128
    int msub = t >> 4, e = t & 15;
    const float* tr = tbuf + (size_t)bd * NN;
    float acc = 0.f;
    for (int m = msub; m < NN; m += 8)
        acc = fmaf(tr[m], c[(((size_t)b << 10) + m) * ND + e], acc);
    acc += __shfl_xor(acc, 16);
    acc += __shfl_xor(acc, 32);
    __shared__ float l2[2][16];
    if ((t & 63) < 16) l2[t >> 6][e] = acc;
    __syncthreads();
    if (t < 16) out[(size_t)bd * ND + t] = l2[0][t] + l2[1][t];
}

extern "C" void kernel_launch(void* const* d_in, const int* in_sizes, int n_in,
                              void* d_out, int out_size, void* d_ws, size_t ws_size,
                              hipStream_t stream) {
    const float* x     = (const float*)d_in[0];
    const float* adj   = (const float*)d_in[1];
    const float* gamma = (const float*)d_in[2];
    const float* beta  = (const float*)d_in[3];
    const float* W     = (const float*)d_in[4];
    const float* bias  = (const float*)d_in[5];
    float* out = (float*)d_out;

    char* wptr = (char*)d_ws;
    size_t used = 0;
    auto alloc = [&](size_t nbytes) -> void* {
        void* p = wptr + used;
        used += (nbytes + 255) & ~(size_t)255;
        return p;
    };
    float* stats   = (float*)alloc(256 * 4);                       // 1 KB (256-aligned)
    float* xsum    = (float*)alloc((size_t)NB * NCI * 4);          // contiguous after stats
    float* ss      = (float*)alloc(256 * 4);
    float* xm      = (float*)alloc((size_t)NB * NCI * 4);
    float* dis     = (float*)alloc((size_t)NB * NN * 4);
    float* selfd   = (float*)alloc((size_t)NB * NN * 4);
    int*   nbr_cnt = (int*)alloc((size_t)NB * NN * 4);
    float* y       = (float*)alloc((size_t)NB * NN * NCI * 4);
    float* blog    = (float*)alloc((size_t)NB * NN * ND * 4);
    float* c       = (float*)alloc((size_t)NB * NN * ND * 4);
    float* psum    = (float*)alloc((size_t)NB * 16 * NCI * 4);
    float* pg      = (float*)alloc((size_t)NB * 32 * ND * NCI * 4);
    float* pcs     = (float*)alloc((size_t)NB * 16 * ND * 4);
    float* hbuf    = (float*)alloc((size_t)NB * ND * NCI * 4);
    float* hbb     = (float*)alloc((size_t)NB * ND * 4);
    float* tbuf    = (float*)alloc((size_t)NB * ND * NN * 4);
    int*   nbr_idx = (int*)alloc((size_t)NB * NN * MAXDEG * 4);
    if (used > ws_size) return;

    // stats (1 KB) + xsum (8 KB) are adjacent: one memset covers both
    hipMemsetAsync(stats, 0, 256 * 4 + (size_t)NB * NCI * 4, stream);

    k_bnstats<<<64, 256, 0, stream>>>(x, stats, xsum);
    k_bnfin<<<NB, 128, 0, stream>>>(stats, xsum, gamma, beta, ss, xm);
    k_nbr<<<NB * NN, 256, 0, stream>>>(adj, dis, nbr_idx, nbr_cnt, selfd);
    k_y<<<NB * NN, 128, 0, stream>>>(x, ss, dis, nbr_idx, nbr_cnt, y);

    // iter 0: c uniform (sparsemax of zeros) -> g = rowsum(y)/16, csum = 64
    k_ysum<<<NB * 16, 128, 0, stream>>>(y, psum);
    k_sv<<<NB * ND, 128, 0, stream>>>(psum, psum, W, bias, xm, hbuf, hbb, out, 0);
    // iter 1
    k_bgc<<<NB * 16, 256, 0, stream>>>(y, hbuf, hbb, blog, c, pg, pcs, 1, 0);
    k_sv<<<NB * ND, 128, 0, stream>>>(pg, pcs, W, bias, xm, hbuf, hbb, out, 1);
    // iter 2 (final c)
    k_bgc<<<NB * 16, 256, 0, stream>>>(y, hbuf, hbb, blog, c, pg, pcs, 0, 1);
    k_sv<<<NB * ND, 128, 0, stream>>>(pg, pcs, W, bias, xm, hbuf, hbb, out, 2);

    k_t2<<<NB * NN, 64, 0, stream>>>(c, nbr_idx, nbr_cnt, selfd, tbuf);
    k_adjout<<<NB * ND, 128, 0, stream>>>(tbuf, c, out + (size_t)NB * ND * NCO);
}

// Round 4
// 196.216 us; speedup vs baseline: 7.1236x; 1.0745x over previous
//
#include <hip/hip_runtime.h>

#define NB 16      // B
#define NN 1024    // N
#define ND 16      // D
#define NCI 128    // CI
#define NCO 128    // CO
#define BN_ROWS (NB*NN)
#define MAXDEG 128

__device__ __forceinline__ void fma4(float4& a, float s, const float4& w) {
    a.x = fmaf(s, w.x, a.x); a.y = fmaf(s, w.y, a.y);
    a.z = fmaf(s, w.z, a.z); a.w = fmaf(s, w.w, a.w);
}
__device__ __forceinline__ void add4(float4& a, const float4& b) {
    a.x += b.x; a.y += b.y; a.z += b.z; a.w += b.w;
}

// ---------------- BatchNorm stats + per-b sums (float4, 256 blocks) ----------------
__global__ __launch_bounds__(256) void k_bnstats(const float* __restrict__ x,
                                                 float* __restrict__ stats,
                                                 float* __restrict__ xsum) {
    int t = threadIdx.x;
    int q = t & 31;        // float4 column
    int rg = t >> 5;       // 0..7
    int row0 = blockIdx.x * 64;
    int b = blockIdx.x >> 4;
    const float4* x4 = (const float4*)x;
    float4 s = make_float4(0, 0, 0, 0), sq = make_float4(0, 0, 0, 0);
    for (int r = rg; r < 64; r += 8) {
        float4 v = x4[(size_t)(row0 + r) * 32 + q];
        s.x += v.x; s.y += v.y; s.z += v.z; s.w += v.w;
        sq.x = fmaf(v.x, v.x, sq.x); sq.y = fmaf(v.y, v.y, sq.y);
        sq.z = fmaf(v.z, v.z, sq.z); sq.w = fmaf(v.w, v.w, sq.w);
    }
    __shared__ float4 ls[8][32], lq[8][32];
    ls[rg][q] = s; lq[rg][q] = sq;
    __syncthreads();
    if (t < 64) {
        int qq = t & 31, which = t >> 5;
        if (which == 0) {
            float4 a = ls[0][qq];
            #pragma unroll
            for (int r = 1; r < 8; ++r) add4(a, ls[r][qq]);
            atomicAdd(&stats[qq * 4 + 0], a.x);
            atomicAdd(&stats[qq * 4 + 1], a.y);
            atomicAdd(&stats[qq * 4 + 2], a.z);
            atomicAdd(&stats[qq * 4 + 3], a.w);
            atomicAdd(&xsum[b * 128 + qq * 4 + 0], a.x);
            atomicAdd(&xsum[b * 128 + qq * 4 + 1], a.y);
            atomicAdd(&xsum[b * 128 + qq * 4 + 2], a.z);
            atomicAdd(&xsum[b * 128 + qq * 4 + 3], a.w);
        } else {
            float4 a = lq[0][qq];
            #pragma unroll
            for (int r = 1; r < 8; ++r) add4(a, lq[r][qq]);
            atomicAdd(&stats[128 + qq * 4 + 0], a.x);
            atomicAdd(&stats[128 + qq * 4 + 1], a.y);
            atomicAdd(&stats[128 + qq * 4 + 2], a.z);
            atomicAdd(&stats[128 + qq * 4 + 3], a.w);
        }
    }
}

// ss (scale/shift) + xm[b,:] = sc*mean_n(x) + sh
__global__ void k_bnfin(const float* __restrict__ stats, const float* __restrict__ xsum,
                        const float* __restrict__ gamma, const float* __restrict__ beta,
                        float* __restrict__ ss, float* __restrict__ xm) {
    int ci = threadIdx.x;
    int b = blockIdx.x;
    float mu = stats[ci] * (1.f / BN_ROWS);
    float var = stats[128 + ci] * (1.f / BN_ROWS) - mu * mu;
    float sc = gamma[ci] * rsqrtf(var + 1e-5f);
    float sh = beta[ci] - mu * sc;
    if (b == 0) { ss[ci] = sc; ss[128 + ci] = sh; }
    xm[b * NCI + ci] = xsum[b * NCI + ci] * (1.f / NN) * sc + sh;
}

// one-time W transpose: Wt[d,o,i] = W[d,i,o]
__global__ void k_wt(const float* __restrict__ W, float* __restrict__ Wt) {
    int d = blockIdx.x;
    int t = threadIdx.x;   // 256
    int r = t >> 5, cq = t & 31;
    __shared__ float tile[32][33];
    const float* Wd = W + (size_t)d * NCI * NCO;
    float* Wtd = Wt + (size_t)d * NCI * NCO;
    for (int ti = 0; ti < 4; ++ti)
        for (int tj = 0; tj < 4; ++tj) {
            __syncthreads();
            for (int rr = r; rr < 32; rr += 8)
                tile[rr][cq] = Wd[(size_t)(ti * 32 + rr) * 128 + tj * 32 + cq];
            __syncthreads();
            for (int rr = r; rr < 32; rr += 8)
                Wtd[(size_t)(tj * 32 + rr) * 128 + ti * 32 + cq] = tile[cq][rr];
        }
}

// ---------------- adjacency: degree + neighbor lists + self-diag flag ----------------
__global__ void k_nbr(const float* __restrict__ adj, float* __restrict__ dis,
                      int* __restrict__ nbr_idx, int* __restrict__ nbr_cnt,
                      float* __restrict__ selfd) {
    int bm = blockIdx.x;              // b*N + m
    int m = bm & (NN - 1);
    const float4* row4 = (const float4*)(adj + (size_t)bm * NN);
    __shared__ int cnt;
    __shared__ int idx[MAXDEG];
    if (threadIdx.x == 0) { cnt = 1; idx[0] = m; }   // forced self-loop
    __syncthreads();
    int t = threadIdx.x;   // 256: one float4 each
    float4 v = row4[t];
    int n0 = t * 4;
    float av[4] = {v.x, v.y, v.z, v.w};
    #pragma unroll
    for (int j = 0; j < 4; ++j) {
        int n = n0 + j;
        if (n == m) {
            selfd[bm] = (av[j] > 0.5f) ? 1.f : 0.f;
        } else if (av[j] > 0.5f) {
            int p = atomicAdd(&cnt, 1);
            if (p < MAXDEG) idx[p] = n;
        }
    }
    __syncthreads();
    int c = min(cnt, MAXDEG);
    if (t == 0) {
        nbr_cnt[bm] = c;
        dis[bm] = rsqrtf((float)c);
    }
    for (int k = t; k < c; k += 256) nbr_idx[(size_t)bm * MAXDEG + k] = idx[k];
}

// ---------------- y = a_norm @ (x*sc+sh)  (sparse gather, affine folded, f4) ----------------
__global__ void k_y(const float* __restrict__ x, const float* __restrict__ ss,
                    const float* __restrict__ dis, const int* __restrict__ nbr_idx,
                    const int* __restrict__ nbr_cnt, float* __restrict__ y) {
    int bm = blockIdx.x;
    int b = bm >> 10;
    int t = threadIdx.x;  // 128
    int q = t & 31, ng = t >> 5;
    __shared__ float sw[MAXDEG];
    __shared__ int sIdx[MAXDEG];
    int cnt = nbr_cnt[bm];
    float dm = dis[bm];
    for (int k = t; k < cnt; k += 128) {
        int n = nbr_idx[(size_t)bm * MAXDEG + k];
        sIdx[k] = n;
        sw[k] = dm * dis[(b << 10) + n];
    }
    __syncthreads();
    const float4* xb = (const float4*)(x + ((size_t)(b << 10)) * NCI);
    float4 acc = make_float4(0, 0, 0, 0);
    float wsum = 0.f;
    for (int k = ng; k < cnt; k += 4) {
        float w = sw[k];
        float4 v = xb[(size_t)sIdx[k] * 32 + q];
        fma4(acc, w, v);
        wsum += w;
    }
    __shared__ float4 lacc[4][32];
    __shared__ float lws[4];
    lacc[ng][q] = acc;
    if (q == 0) lws[ng] = wsum;
    __syncthreads();
    if (t < 32) {
        float4 a = lacc[0][t];
        add4(a, lacc[1][t]); add4(a, lacc[2][t]); add4(a, lacc[3][t]);
        float wst = lws[0] + lws[1] + lws[2] + lws[3];
        float4 sc = ((const float4*)ss)[t];
        float4 sh = ((const float4*)(ss + 128))[t];
        float4 o;
        o.x = sc.x * a.x + sh.x * wst;
        o.y = sc.y * a.y + sh.y * wst;
        o.z = sc.z * a.z + sh.z * wst;
        o.w = sc.w * a.w + sh.w * wst;
        ((float4*)(y + (size_t)bm * NCI))[t] = o;
    }
}

// partial row-sums of y: psum[b,ch,i] = sum_{64 rows} y   (iter-0 uniform c)
__global__ __launch_bounds__(256) void k_ysum(const float* __restrict__ y,
                                              float* __restrict__ psum) {
    int blk = blockIdx.x; int b = blk >> 4, ch = blk & 15;
    int t = threadIdx.x;  // 256
    int q = t & 31, rg = t >> 5;
    const float4* yb = (const float4*)(y + (((size_t)b << 10) + ch * 64) * NCI);
    float4 s = make_float4(0, 0, 0, 0);
    for (int n = rg; n < 64; n += 8) {
        float4 v = yb[(size_t)n * 32 + q];
        add4(s, v);
    }
    __shared__ float4 ls[8][32];
    ls[rg][q] = s;
    __syncthreads();
    if (t < 32) {
        float4 a = ls[0][t];
        #pragma unroll
        for (int r = 1; r < 8; ++r) add4(a, ls[r][t]);
        ((float4*)(psum + ((size_t)b * 16 + ch) * NCI))[t] = a;
    }
}

// s->v->h fused, 256 threads, coalesced f4 via W and Wt.
// mode 0: g from psum (uniform c); mode 1: g from pg/pcs; mode 2: final output
__global__ __launch_bounds__(256) void k_sv(const float* __restrict__ gsrc,
                     const float* __restrict__ pcs,
                     const float* __restrict__ W, const float* __restrict__ Wt,
                     const float* __restrict__ bias,
                     const float* __restrict__ xm, float* __restrict__ hbuf,
                     float* __restrict__ hbb, float* __restrict__ outv, int mode) {
    int bd = blockIdx.x; int b = bd >> 4, d = bd & 15;
    int t = threadIdx.x;  // 256
    __shared__ float gl[128];
    __shared__ float csum_s;
    __shared__ float4 red[8][32];
    __shared__ float redf[256];
    __shared__ float svec[128];
    __shared__ float vv[128];
    __shared__ float scal;

    // 1. g reduction
    {
        int col = t & 127, half = t >> 7;
        float g = 0.f;
        if (mode == 0) {
            #pragma unroll
            for (int ch = half * 8; ch < half * 8 + 8; ++ch)
                g += gsrc[((size_t)b * 16 + ch) * NCI + col];
            g *= (1.f / 16.f);
        } else {
            #pragma unroll
            for (int ch = half * 16; ch < half * 16 + 16; ++ch)
                g += gsrc[(((size_t)b * 32 + ch) * 16 + d) * NCI + col];
        }
        ((float*)red)[half * 128 + col] = g;
        if (t == 0) {
            if (mode == 0) csum_s = 64.f;
            else {
                float cs = 0.f;
                #pragma unroll
                for (int ch = 0; ch < 16; ++ch) cs += pcs[(b * 16 + ch) * 16 + d];
                csum_s = cs;
            }
        }
    }
    __syncthreads();
    if (t < 128) gl[t] = ((float*)red)[t] + ((float*)red)[128 + t];
    __syncthreads();

    // 2. s[o] = sum_i gl[i]*W[d,i,o] + csum*bias[o]
    {
        int q = t & 31, hh = t >> 5;
        const float4* Wd4 = (const float4*)(W + (size_t)d * NCI * NCO);
        float4 acc = make_float4(0, 0, 0, 0);
        for (int i = hh * 16; i < hh * 16 + 16; ++i)
            fma4(acc, gl[i], Wd4[(size_t)i * 32 + q]);
        red[hh][q] = acc;
    }
    __syncthreads();
    if (t < 32) {
        float4 a = red[0][t];
        #pragma unroll
        for (int r = 1; r < 8; ++r) add4(a, red[r][t]);
        float4 b4 = ((const float4*)(bias + d * NCO))[t];
        float cs = csum_s;
        a.x = fmaf(cs, b4.x, a.x); a.y = fmaf(cs, b4.y, a.y);
        a.z = fmaf(cs, b4.z, a.z); a.w = fmaf(cs, b4.w, a.w);
        ((float4*)svec)[t] = a;
    }
    __syncthreads();

    if (mode == 2) {
        if (t < 128) {
            float sv2 = svec[t] + xm[b * NCO + t];
            float sq = sv2 * sv2;
            outv[(size_t)bd * NCO + t] = (sq / (1.f + sq)) * sv2 * rsqrtf(sq + 1e-8f);
        }
        return;
    }

    // 3. squash over o
    redf[t] = (t < 128) ? svec[t] * svec[t] : 0.f;
    __syncthreads();
    if (t < 64) {
        float val = redf[t] + redf[t + 64] + redf[t + 128] + redf[t + 192];
        #pragma unroll
        for (int m2 = 32; m2 >= 1; m2 >>= 1) val += __shfl_xor(val, m2);
        if (t == 0) scal = val;
    }
    __syncthreads();
    if (t < 128) {
        float tot = scal;
        vv[t] = (tot / (1.f + tot)) * svec[t] * rsqrtf(tot + 1e-8f);
    }
    __syncthreads();

    // 4. h[i] = sum_o Wt[d,o,i]*vv[o]  (coalesced via Wt)
    {
        int q = t & 31, hh = t >> 5;
        const float4* Wt4 = (const float4*)(Wt + (size_t)d * NCI * NCO);
        float4 acc = make_float4(0, 0, 0, 0);
        for (int o = hh * 16; o < hh * 16 + 16; ++o)
            fma4(acc, vv[o], Wt4[(size_t)o * 32 + q]);
        red[hh][q] = acc;
    }
    redf[t] = (t < 128) ? bias[d * NCO + t] * vv[t] : 0.f;
    __syncthreads();
    if (t < 32) {
        float4 a = red[0][t];
        #pragma unroll
        for (int r = 1; r < 8; ++r) add4(a, red[r][t]);
        ((float4*)(hbuf + (size_t)bd * NCI))[t] = a;
    }
    if (t >= 64 && t < 128) {
        int tt = t - 64;
        float val = redf[tt] + redf[tt + 64] + redf[tt + 128] + redf[tt + 192];
        #pragma unroll
        for (int m2 = 32; m2 >= 1; m2 >>= 1) val += __shfl_xor(val, m2);
        if (tt == 0) hbb[bd] = val;
    }
}

// fused: blog update + sparsemax + g partials (+ optional global c write)
__global__ __launch_bounds__(256) void k_bgc(const float* __restrict__ y,
        const float* __restrict__ hbuf, const float* __restrict__ hbb,
        float* __restrict__ blog, float* __restrict__ cglob,
        float* __restrict__ pg, float* __restrict__ pcs, int first, int last) {
    int blk = blockIdx.x; int b = blk >> 4, ch = blk & 15;
    int t = threadIdx.x;  // 256
    int n0 = ch * 64;
    __shared__ __align__(16) float sh[16 * 128];
    __shared__ __align__(16) float sy[64 * 128];
    __shared__ float shb[16];
    __shared__ float scd[64][17];
    {
        const float4* hb4 = (const float4*)(hbuf + (size_t)b * 16 * NCI);
        float4* sh4 = (float4*)sh;
        for (int j = t; j < 16 * 32; j += 256) sh4[j] = hb4[j];
        const float4* yb4 = (const float4*)(y + (((size_t)b << 10) + n0) * NCI);
        float4* sy4 = (float4*)sy;
        for (int j = t; j < 64 * 32; j += 256) sy4[j] = yb4[j];
        if (t < 16) shb[t] = hbb[b * 16 + t];
    }
    __syncthreads();
    int nsub = t >> 4, d = t & 15;
    for (int nn = nsub; nn < 64; nn += 16) {
        float acc = 0.f;
        const float* yr = &sy[nn * 128];
        const float* hr = &sh[d * 128];
        #pragma unroll 8
        for (int i = 0; i < 128; i += 4) {
            float4 a = *(const float4*)&yr[i];
            float4 h4 = *(const float4*)&hr[i];
            acc = fmaf(a.x, h4.x, acc);
            acc = fmaf(a.y, h4.y, acc);
            acc = fmaf(a.z, h4.z, acc);
            acc = fmaf(a.w, h4.w, acc);
        }
        size_t idx = (((size_t)b << 10) + n0 + nn) * ND + d;
        float bnew = acc + shb[d] + (first ? 0.f : blog[idx]);
        if (!last) blog[idx] = bnew;
        scd[nn][d] = bnew;
    }
    __syncthreads();
    if (t < 64) {
        float z[16], zs[16];
        #pragma unroll
        for (int d2 = 0; d2 < 16; ++d2) { z[d2] = scd[t][d2]; zs[d2] = z[d2]; }
        #pragma unroll
        for (int a = 0; a < 16; ++a) {
            #pragma unroll
            for (int b2 = a + 1; b2 < 16; ++b2) {
                float hi = fmaxf(zs[a], zs[b2]);
                float lo = fminf(zs[a], zs[b2]);
                zs[a] = hi; zs[b2] = lo;
            }
        }
        float cs = 0.f, tausum = 0.f;
        int kz = 1;
        #pragma unroll
        for (int k = 1; k <= 16; ++k) {
            cs += zs[k - 1];
            if (1.f + (float)k * zs[k - 1] > cs) { kz = k; tausum = cs; }
        }
        float tau = (tausum - 1.f) / (float)kz;
        #pragma unroll
        for (int d2 = 0; d2 < 16; ++d2) scd[t][d2] = fmaxf(z[d2] - tau, 0.f);
    }
    __syncthreads();
    if (last) {
        for (int j = t; j < 64 * 16; j += 256)
            cglob[(((size_t)b << 10) + n0 + (j >> 4)) * ND + (j & 15)] = scd[j >> 4][j & 15];
    }
    if (t < 16) {
        float cs = 0.f;
        #pragma unroll 4
        for (int nn = 0; nn < 64; ++nn) cs += scd[nn][t];
        pcs[(b * 16 + ch) * 16 + t] = cs;
    }
    int col = t & 127, h2 = t >> 7;
    float accg[16] = {};
    for (int nn = 0; nn < 32; ++nn) {
        int r = h2 * 32 + nn;
        float yv = sy[r * 128 + col];
        #pragma unroll
        for (int d2 = 0; d2 < 16; ++d2) accg[d2] = fmaf(scd[r][d2], yv, accg[d2]);
    }
    #pragma unroll
    for (int d2 = 0; d2 < 16; ++d2)
        pg[(((size_t)b * 32 + ch * 2 + h2) * 16 + d2) * NCI + col] = accg[d2];
}

// ---------------- adj_out via neighbor lists ----------------
__global__ void k_t2(const float* __restrict__ c, const int* __restrict__ nbr_idx,
                     const int* __restrict__ nbr_cnt, const float* __restrict__ selfd,
                     float* __restrict__ tbuf) {
    int bm = blockIdx.x; int b = bm >> 10, m = bm & 1023;
    int t = threadIdx.x;  // 64
    int nsub = t >> 4, d = t & 15;
    int cnt = nbr_cnt[bm];
    float acc = 0.f;
    for (int k = nsub; k < cnt; k += 4) {
        int n = nbr_idx[(size_t)bm * MAXDEG + k];
        acc += c[(((size_t)b << 10) + n) * ND + d];
    }
    acc += __shfl_xor(acc, 16);
    acc += __shfl_xor(acc, 32);
    if (t < 16) {
        if (selfd[bm] == 0.f) acc -= c[(size_t)bm * ND + d];
        tbuf[((size_t)b * 16 + d) * NN + m] = acc;
    }
}

__global__ void k_adjout(const float* __restrict__ tbuf, const float* __restrict__ c,
                         float* __restrict__ out) {
    int bd = blockIdx.x; int b = bd >> 4;
    int t = threadIdx.x;  // 128
    int msub = t >> 4, e = t & 15;
    const float* tr = tbuf + (size_t)bd * NN;
    float acc = 0.f;
    for (int m = msub; m < NN; m += 8)
        acc = fmaf(tr[m], c[(((size_t)b << 10) + m) * ND + e], acc);
    acc += __shfl_xor(acc, 16);
    acc += __shfl_xor(acc, 32);
    __shared__ float l2[2][16];
    if ((t & 63) < 16) l2[t >> 6][e] = acc;
    __syncthreads();
    if (t < 16) out[(size_t)bd * ND + t] = l2[0][t] + l2[1][t];
}

extern "C" void kernel_launch(void* const* d_in, const int* in_sizes, int n_in,
                              void* d_out, int out_size, void* d_ws, size_t ws_size,
                              hipStream_t stream) {
    const float* x     = (const float*)d_in[0];
    const float* adj   = (const float*)d_in[1];
    const float* gamma = (const float*)d_in[2];
    const float* beta  = (const float*)d_in[3];
    const float* W     = (const float*)d_in[4];
    const float* bias  = (const float*)d_in[5];
    float* out = (float*)d_out;

    char* wptr = (char*)d_ws;
    size_t used = 0;
    auto alloc = [&](size_t nbytes) -> void* {
        void* p = wptr + used;
        used += (nbytes + 255) & ~(size_t)255;
        return p;
    };
    float* stats   = (float*)alloc(256 * 4);
    float* xsum    = (float*)alloc((size_t)NB * NCI * 4);   // adjacent to stats
    float* ss      = (float*)alloc(256 * 4);
    float* xm      = (float*)alloc((size_t)NB * NCI * 4);
    float* dis     = (float*)alloc((size_t)NB * NN * 4);
    float* selfd   = (float*)alloc((size_t)NB * NN * 4);
    int*   nbr_cnt = (int*)alloc((size_t)NB * NN * 4);
    float* Wt      = (float*)alloc((size_t)ND * NCI * NCO * 4);
    float* y       = (float*)alloc((size_t)NB * NN * NCI * 4);
    float* blog    = (float*)alloc((size_t)NB * NN * ND * 4);
    float* c       = (float*)alloc((size_t)NB * NN * ND * 4);
    float* psum    = (float*)alloc((size_t)NB * 16 * NCI * 4);
    float* pg      = (float*)alloc((size_t)NB * 32 * ND * NCI * 4);
    float* pcs     = (float*)alloc((size_t)NB * 16 * ND * 4);
    float* hbuf    = (float*)alloc((size_t)NB * ND * NCI * 4);
    float* hbb     = (float*)alloc((size_t)NB * ND * 4);
    float* tbuf    = (float*)alloc((size_t)NB * ND * NN * 4);
    int*   nbr_idx = (int*)alloc((size_t)NB * NN * MAXDEG * 4);
    if (used > ws_size) return;

    hipMemsetAsync(stats, 0, 256 * 4 + (size_t)NB * NCI * 4, stream);

    k_bnstats<<<256, 256, 0, stream>>>(x, stats, xsum);
    k_bnfin<<<NB, 128, 0, stream>>>(stats, xsum, gamma, beta, ss, xm);
    k_wt<<<ND, 256, 0, stream>>>(W, Wt);
    k_nbr<<<NB * NN, 256, 0, stream>>>(adj, dis, nbr_idx, nbr_cnt, selfd);
    k_y<<<NB * NN, 128, 0, stream>>>(x, ss, dis, nbr_idx, nbr_cnt, y);

    // iter 0: c uniform (sparsemax of zeros) -> g = rowsum(y)/16, csum = 64
    k_ysum<<<NB * 16, 256, 0, stream>>>(y, psum);
    k_sv<<<NB * ND, 256, 0, stream>>>(psum, psum, W, Wt, bias, xm, hbuf, hbb, out, 0);
    // iter 1
    k_bgc<<<NB * 16, 256, 0, stream>>>(y, hbuf, hbb, blog, c, pg, pcs, 1, 0);
    k_sv<<<NB * ND, 256, 0, stream>>>(pg, pcs, W, Wt, bias, xm, hbuf, hbb, out, 1);
    // iter 2 (final c)
    k_bgc<<<NB * 16, 256, 0, stream>>>(y, hbuf, hbb, blog, c, pg, pcs, 0, 1);
    k_sv<<<NB * ND, 256, 0, stream>>>(pg, pcs, W, Wt, bias, xm, hbuf, hbb, out, 2);

    k_t2<<<NB * NN, 64, 0, stream>>>(c, nbr_idx, nbr_cnt, selfd, tbuf);
    k_adjout<<<NB * ND, 128, 0, stream>>>(tbuf, c, out + (size_t)NB * ND * NCO);
}

// Round 5
// 170.933 us; speedup vs baseline: 8.1773x; 1.1479x over previous
//
#include <hip/hip_runtime.h>

#define NB 16      // B
#define NN 1024    // N
#define ND 16      // D
#define NCI 128    // CI
#define NCO 128    // CO
#define BN_ROWS (NB*NN)
#define MAXDEG 128

__device__ __forceinline__ void fma4(float4& a, float s, const float4& w) {
    a.x = fmaf(s, w.x, a.x); a.y = fmaf(s, w.y, a.y);
    a.z = fmaf(s, w.z, a.z); a.w = fmaf(s, w.w, a.w);
}
__device__ __forceinline__ void add4(float4& a, const float4& b) {
    a.x += b.x; a.y += b.y; a.z += b.z; a.w += b.w;
}

// ---------------- fused: BN partial stats (blocks 0..255) + W transpose (blocks 256..271) ----
// pbn[blk][0:128] = partial sum, pbn[blk][128:256] = partial sumsq  (full overwrite, no zeroing)
__global__ __launch_bounds__(256) void k_pre1(const float* __restrict__ x,
                                              float* __restrict__ pbn,
                                              const float* __restrict__ W,
                                              float* __restrict__ Wt) {
    __shared__ float4 ls[8][32], lq[8][32];
    __shared__ float tile[32][33];
    int t = threadIdx.x;
    if (blockIdx.x < 256) {
        int q = t & 31, rg = t >> 5;
        int row0 = blockIdx.x * 64;
        const float4* x4 = (const float4*)x;
        float4 s = make_float4(0, 0, 0, 0), sq = make_float4(0, 0, 0, 0);
        for (int r = rg; r < 64; r += 8) {
            float4 v = x4[(size_t)(row0 + r) * 32 + q];
            s.x += v.x; s.y += v.y; s.z += v.z; s.w += v.w;
            sq.x = fmaf(v.x, v.x, sq.x); sq.y = fmaf(v.y, v.y, sq.y);
            sq.z = fmaf(v.z, v.z, sq.z); sq.w = fmaf(v.w, v.w, sq.w);
        }
        ls[rg][q] = s; lq[rg][q] = sq;
        __syncthreads();
        if (t < 32) {
            float4 a = ls[0][t];
            #pragma unroll
            for (int r = 1; r < 8; ++r) add4(a, ls[r][t]);
            ((float4*)(pbn + (size_t)blockIdx.x * 256))[t] = a;
        } else if (t < 64) {
            int qq = t - 32;
            float4 a = lq[0][qq];
            #pragma unroll
            for (int r = 1; r < 8; ++r) add4(a, lq[r][qq]);
            ((float4*)(pbn + (size_t)blockIdx.x * 256 + 128))[qq] = a;
        }
    } else {
        int d = blockIdx.x - 256;
        int r = t >> 5, cq = t & 31;
        const float* Wd = W + (size_t)d * NCI * NCO;
        float* Wtd = Wt + (size_t)d * NCI * NCO;
        for (int ti = 0; ti < 4; ++ti)
            for (int tj = 0; tj < 4; ++tj) {
                __syncthreads();
                for (int rr = r; rr < 32; rr += 8)
                    tile[rr][cq] = Wd[(size_t)(ti * 32 + rr) * 128 + tj * 32 + cq];
                __syncthreads();
                for (int rr = r; rr < 32; rr += 8)
                    Wtd[(size_t)(tj * 32 + rr) * 128 + ti * 32 + cq] = tile[cq][rr];
            }
    }
}

// ---------------- fused: neighbor lists (blocks 0..16383) + BN finalize (blocks 16384..16399) ----
__global__ __launch_bounds__(256) void k_pre2(const float* __restrict__ adj,
        float* __restrict__ dis, int* __restrict__ nbr_idx, int* __restrict__ nbr_cnt,
        float* __restrict__ selfd, const float* __restrict__ pbn,
        const float* __restrict__ gamma, const float* __restrict__ beta,
        float* __restrict__ ss, float* __restrict__ xm) {
    int t = threadIdx.x;
    if (blockIdx.x < NB * NN) {
        int bm = blockIdx.x;              // b*N + m
        int m = bm & (NN - 1);
        const float4* row4 = (const float4*)(adj + (size_t)bm * NN);
        __shared__ int cnt;
        __shared__ int idx[MAXDEG];
        if (t == 0) { cnt = 1; idx[0] = m; }   // forced self-loop
        __syncthreads();
        float4 v = row4[t];
        int n0 = t * 4;
        float av[4] = {v.x, v.y, v.z, v.w};
        #pragma unroll
        for (int j = 0; j < 4; ++j) {
            int n = n0 + j;
            if (n == m) {
                selfd[bm] = (av[j] > 0.5f) ? 1.f : 0.f;
            } else if (av[j] > 0.5f) {
                int p = atomicAdd(&cnt, 1);
                if (p < MAXDEG) idx[p] = n;
            }
        }
        __syncthreads();
        int c = min(cnt, MAXDEG);
        if (t == 0) {
            nbr_cnt[bm] = c;
            dis[bm] = rsqrtf((float)c);
        }
        for (int k = t; k < c; k += 256) nbr_idx[(size_t)bm * MAXDEG + k] = idx[k];
    } else {
        int b = blockIdx.x - NB * NN;   // 0..15
        if (t < 128) {
            float s = 0.f, sq = 0.f, sb = 0.f;
            for (int blk = 0; blk < 256; ++blk) {
                float v = pbn[(size_t)blk * 256 + t];
                s += v;
                sq += pbn[(size_t)blk * 256 + 128 + t];
                sb += ((blk >> 4) == b) ? v : 0.f;
            }
            float mu = s * (1.f / BN_ROWS);
            float var = sq * (1.f / BN_ROWS) - mu * mu;
            float sc = gamma[t] * rsqrtf(var + 1e-5f);
            float sh = beta[t] - mu * sc;
            if (b == 0) { ss[t] = sc; ss[128 + t] = sh; }
            xm[b * NCI + t] = sb * (1.f / NN) * sc + sh;
        }
    }
}

// ---------------- y = a_norm @ (x*sc+sh)  (sparse gather, affine folded, f4) ----------------
__global__ void k_y(const float* __restrict__ x, const float* __restrict__ ss,
                    const float* __restrict__ dis, const int* __restrict__ nbr_idx,
                    const int* __restrict__ nbr_cnt, float* __restrict__ y) {
    int bm = blockIdx.x;
    int b = bm >> 10;
    int t = threadIdx.x;  // 128
    int q = t & 31, ng = t >> 5;
    __shared__ float sw[MAXDEG];
    __shared__ int sIdx[MAXDEG];
    int cnt = nbr_cnt[bm];
    float dm = dis[bm];
    for (int k = t; k < cnt; k += 128) {
        int n = nbr_idx[(size_t)bm * MAXDEG + k];
        sIdx[k] = n;
        sw[k] = dm * dis[(b << 10) + n];
    }
    __syncthreads();
    const float4* xb = (const float4*)(x + ((size_t)(b << 10)) * NCI);
    float4 acc = make_float4(0, 0, 0, 0);
    float wsum = 0.f;
    for (int k = ng; k < cnt; k += 4) {
        float w = sw[k];
        float4 v = xb[(size_t)sIdx[k] * 32 + q];
        fma4(acc, w, v);
        wsum += w;
    }
    __shared__ float4 lacc[4][32];
    __shared__ float lws[4];
    lacc[ng][q] = acc;
    if (q == 0) lws[ng] = wsum;
    __syncthreads();
    if (t < 32) {
        float4 a = lacc[0][t];
        add4(a, lacc[1][t]); add4(a, lacc[2][t]); add4(a, lacc[3][t]);
        float wst = lws[0] + lws[1] + lws[2] + lws[3];
        float4 sc = ((const float4*)ss)[t];
        float4 sh = ((const float4*)(ss + 128))[t];
        float4 o;
        o.x = sc.x * a.x + sh.x * wst;
        o.y = sc.y * a.y + sh.y * wst;
        o.z = sc.z * a.z + sh.z * wst;
        o.w = sc.w * a.w + sh.w * wst;
        ((float4*)(y + (size_t)bm * NCI))[t] = o;
    }
}

// partial row-sums of y: psum[b,ch,i] = sum_{64 rows} y   (iter-0 uniform c)
__global__ __launch_bounds__(256) void k_ysum(const float* __restrict__ y,
                                              float* __restrict__ psum) {
    int blk = blockIdx.x; int b = blk >> 4, ch = blk & 15;
    int t = threadIdx.x;  // 256
    int q = t & 31, rg = t >> 5;
    const float4* yb = (const float4*)(y + (((size_t)b << 10) + ch * 64) * NCI);
    float4 s = make_float4(0, 0, 0, 0);
    for (int n = rg; n < 64; n += 8) {
        float4 v = yb[(size_t)n * 32 + q];
        add4(s, v);
    }
    __shared__ float4 ls[8][32];
    ls[rg][q] = s;
    __syncthreads();
    if (t < 32) {
        float4 a = ls[0][t];
        #pragma unroll
        for (int r = 1; r < 8; ++r) add4(a, ls[r][t]);
        ((float4*)(psum + ((size_t)b * 16 + ch) * NCI))[t] = a;
    }
}

// s->v->h fused, 256 threads, coalesced f4 via W and Wt.
// mode 0: g from psum (uniform c); mode 1: g from pg/pcs; mode 2: final output
__global__ __launch_bounds__(256) void k_sv(const float* __restrict__ gsrc,
                     const float* __restrict__ pcs,
                     const float* __restrict__ W, const float* __restrict__ Wt,
                     const float* __restrict__ bias,
                     const float* __restrict__ xm, float* __restrict__ hbuf,
                     float* __restrict__ hbb, float* __restrict__ outv, int mode) {
    int bd = blockIdx.x; int b = bd >> 4, d = bd & 15;
    int t = threadIdx.x;  // 256
    __shared__ float gl[128];
    __shared__ float csum_s;
    __shared__ float4 red[8][32];
    __shared__ float redf[256];
    __shared__ float svec[128];
    __shared__ float vv[128];
    __shared__ float scal;

    // 1. g reduction
    {
        int col = t & 127, half = t >> 7;
        float g = 0.f;
        if (mode == 0) {
            #pragma unroll
            for (int ch = half * 8; ch < half * 8 + 8; ++ch)
                g += gsrc[((size_t)b * 16 + ch) * NCI + col];
            g *= (1.f / 16.f);
        } else {
            #pragma unroll
            for (int ch = half * 16; ch < half * 16 + 16; ++ch)
                g += gsrc[(((size_t)b * 32 + ch) * 16 + d) * NCI + col];
        }
        ((float*)red)[half * 128 + col] = g;
        if (t == 0) {
            if (mode == 0) csum_s = 64.f;
            else {
                float cs = 0.f;
                #pragma unroll
                for (int ch = 0; ch < 16; ++ch) cs += pcs[(b * 16 + ch) * 16 + d];
                csum_s = cs;
            }
        }
    }
    __syncthreads();
    if (t < 128) gl[t] = ((float*)red)[t] + ((float*)red)[128 + t];
    __syncthreads();

    // 2. s[o] = sum_i gl[i]*W[d,i,o] + csum*bias[o]
    {
        int q = t & 31, hh = t >> 5;
        const float4* Wd4 = (const float4*)(W + (size_t)d * NCI * NCO);
        float4 acc = make_float4(0, 0, 0, 0);
        for (int i = hh * 16; i < hh * 16 + 16; ++i)
            fma4(acc, gl[i], Wd4[(size_t)i * 32 + q]);
        red[hh][q] = acc;
    }
    __syncthreads();
    if (t < 32) {
        float4 a = red[0][t];
        #pragma unroll
        for (int r = 1; r < 8; ++r) add4(a, red[r][t]);
        float4 b4 = ((const float4*)(bias + d * NCO))[t];
        float cs = csum_s;
        a.x = fmaf(cs, b4.x, a.x); a.y = fmaf(cs, b4.y, a.y);
        a.z = fmaf(cs, b4.z, a.z); a.w = fmaf(cs, b4.w, a.w);
        ((float4*)svec)[t] = a;
    }
    __syncthreads();

    if (mode == 2) {
        if (t < 128) {
            float sv2 = svec[t] + xm[b * NCO + t];
            float sq = sv2 * sv2;
            outv[(size_t)bd * NCO + t] = (sq / (1.f + sq)) * sv2 * rsqrtf(sq + 1e-8f);
        }
        return;
    }

    // 3. squash over o
    redf[t] = (t < 128) ? svec[t] * svec[t] : 0.f;
    __syncthreads();
    if (t < 64) {
        float val = redf[t] + redf[t + 64] + redf[t + 128] + redf[t + 192];
        #pragma unroll
        for (int m2 = 32; m2 >= 1; m2 >>= 1) val += __shfl_xor(val, m2);
        if (t == 0) scal = val;
    }
    __syncthreads();
    if (t < 128) {
        float tot = scal;
        vv[t] = (tot / (1.f + tot)) * svec[t] * rsqrtf(tot + 1e-8f);
    }
    __syncthreads();

    // 4. h[i] = sum_o Wt[d,o,i]*vv[o]  (coalesced via Wt)
    {
        int q = t & 31, hh = t >> 5;
        const float4* Wt4 = (const float4*)(Wt + (size_t)d * NCI * NCO);
        float4 acc = make_float4(0, 0, 0, 0);
        for (int o = hh * 16; o < hh * 16 + 16; ++o)
            fma4(acc, vv[o], Wt4[(size_t)o * 32 + q]);
        red[hh][q] = acc;
    }
    redf[t] = (t < 128) ? bias[d * NCO + t] * vv[t] : 0.f;
    __syncthreads();
    if (t < 32) {
        float4 a = red[0][t];
        #pragma unroll
        for (int r = 1; r < 8; ++r) add4(a, red[r][t]);
        ((float4*)(hbuf + (size_t)bd * NCI))[t] = a;
    }
    if (t >= 64 && t < 128) {
        int tt = t - 64;
        float val = redf[tt] + redf[tt + 64] + redf[tt + 128] + redf[tt + 192];
        #pragma unroll
        for (int m2 = 32; m2 >= 1; m2 >>= 1) val += __shfl_xor(val, m2);
        if (tt == 0) hbb[bd] = val;
    }
}

// fused: blog update + sparsemax + g partials (+ optional global c write)
__global__ __launch_bounds__(256) void k_bgc(const float* __restrict__ y,
        const float* __restrict__ hbuf, const float* __restrict__ hbb,
        float* __restrict__ blog, float* __restrict__ cglob,
        float* __restrict__ pg, float* __restrict__ pcs, int first, int last) {
    int blk = blockIdx.x; int b = blk >> 4, ch = blk & 15;
    int t = threadIdx.x;  // 256
    int n0 = ch * 64;
    __shared__ __align__(16) float sh[16 * 128];
    __shared__ __align__(16) float sy[64 * 128];
    __shared__ float shb[16];
    __shared__ float scd[64][17];
    {
        const float4* hb4 = (const float4*)(hbuf + (size_t)b * 16 * NCI);
        float4* sh4 = (float4*)sh;
        for (int j = t; j < 16 * 32; j += 256) sh4[j] = hb4[j];
        const float4* yb4 = (const float4*)(y + (((size_t)b << 10) + n0) * NCI);
        float4* sy4 = (float4*)sy;
        for (int j = t; j < 64 * 32; j += 256) sy4[j] = yb4[j];
        if (t < 16) shb[t] = hbb[b * 16 + t];
    }
    __syncthreads();
    int nsub = t >> 4, d = t & 15;
    for (int nn = nsub; nn < 64; nn += 16) {
        float acc = 0.f;
        const float* yr = &sy[nn * 128];
        const float* hr = &sh[d * 128];
        #pragma unroll 8
        for (int i = 0; i < 128; i += 4) {
            float4 a = *(const float4*)&yr[i];
            float4 h4 = *(const float4*)&hr[i];
            acc = fmaf(a.x, h4.x, acc);
            acc = fmaf(a.y, h4.y, acc);
            acc = fmaf(a.z, h4.z, acc);
            acc = fmaf(a.w, h4.w, acc);
        }
        size_t idx = (((size_t)b << 10) + n0 + nn) * ND + d;
        float bnew = acc + shb[d] + (first ? 0.f : blog[idx]);
        if (!last) blog[idx] = bnew;
        scd[nn][d] = bnew;
    }
    __syncthreads();
    if (t < 64) {
        float z[16], zs[16];
        #pragma unroll
        for (int d2 = 0; d2 < 16; ++d2) { z[d2] = scd[t][d2]; zs[d2] = z[d2]; }
        #pragma unroll
        for (int a = 0; a < 16; ++a) {
            #pragma unroll
            for (int b2 = a + 1; b2 < 16; ++b2) {
                float hi = fmaxf(zs[a], zs[b2]);
                float lo = fminf(zs[a], zs[b2]);
                zs[a] = hi; zs[b2] = lo;
            }
        }
        float cs = 0.f, tausum = 0.f;
        int kz = 1;
        #pragma unroll
        for (int k = 1; k <= 16; ++k) {
            cs += zs[k - 1];
            if (1.f + (float)k * zs[k - 1] > cs) { kz = k; tausum = cs; }
        }
        float tau = (tausum - 1.f) / (float)kz;
        #pragma unroll
        for (int d2 = 0; d2 < 16; ++d2) scd[t][d2] = fmaxf(z[d2] - tau, 0.f);
    }
    __syncthreads();
    if (last) {
        for (int j = t; j < 64 * 16; j += 256)
            cglob[(((size_t)b << 10) + n0 + (j >> 4)) * ND + (j & 15)] = scd[j >> 4][j & 15];
    }
    if (t < 16) {
        float cs = 0.f;
        #pragma unroll 4
        for (int nn = 0; nn < 64; ++nn) cs += scd[nn][t];
        pcs[(b * 16 + ch) * 16 + t] = cs;
    }
    int col = t & 127, h2 = t >> 7;
    float accg[16] = {};
    for (int nn = 0; nn < 32; ++nn) {
        int r = h2 * 32 + nn;
        float yv = sy[r * 128 + col];
        #pragma unroll
        for (int d2 = 0; d2 < 16; ++d2) accg[d2] = fmaf(scd[r][d2], yv, accg[d2]);
    }
    #pragma unroll
    for (int d2 = 0; d2 < 16; ++d2)
        pg[(((size_t)b * 32 + ch * 2 + h2) * 16 + d2) * NCI + col] = accg[d2];
}

// ---------------- adj_out via neighbor lists (4 m-rows per block) ----------------
__global__ __launch_bounds__(256) void k_t2(const float* __restrict__ c,
                     const int* __restrict__ nbr_idx,
                     const int* __restrict__ nbr_cnt, const float* __restrict__ selfd,
                     float* __restrict__ tbuf) {
    int t = threadIdx.x;          // 256 = 4 waves of 64, one m each
    int bm = blockIdx.x * 4 + (t >> 6);
    int b = bm >> 10, m = bm & 1023;
    int tg = t & 63;
    int nsub = tg >> 4, d = tg & 15;
    int cnt = nbr_cnt[bm];
    float acc = 0.f;
    for (int k = nsub; k < cnt; k += 4) {
        int n = nbr_idx[(size_t)bm * MAXDEG + k];
        acc += c[(((size_t)b << 10) + n) * ND + d];
    }
    acc += __shfl_xor(acc, 16);
    acc += __shfl_xor(acc, 32);
    if (tg < 16) {
        if (selfd[bm] == 0.f) acc -= c[(size_t)bm * ND + d];
        tbuf[((size_t)b * 16 + d) * NN + m] = acc;
    }
}

__global__ void k_adjout(const float* __restrict__ tbuf, const float* __restrict__ c,
                         float* __restrict__ out) {
    int bd = blockIdx.x; int b = bd >> 4;
    int t = threadIdx.x;  // 128
    int msub = t >> 4, e = t & 15;
    const float* tr = tbuf + (size_t)bd * NN;
    float acc = 0.f;
    for (int m = msub; m < NN; m += 8)
        acc = fmaf(tr[m], c[(((size_t)b << 10) + m) * ND + e], acc);
    acc += __shfl_xor(acc, 16);
    acc += __shfl_xor(acc, 32);
    __shared__ float l2[2][16];
    if ((t & 63) < 16) l2[t >> 6][e] = acc;
    __syncthreads();
    if (t < 16) out[(size_t)bd * ND + t] = l2[0][t] + l2[1][t];
}

extern "C" void kernel_launch(void* const* d_in, const int* in_sizes, int n_in,
                              void* d_out, int out_size, void* d_ws, size_t ws_size,
                              hipStream_t stream) {
    const float* x     = (const float*)d_in[0];
    const float* adj   = (const float*)d_in[1];
    const float* gamma = (const float*)d_in[2];
    const float* beta  = (const float*)d_in[3];
    const float* W     = (const float*)d_in[4];
    const float* bias  = (const float*)d_in[5];
    float* out = (float*)d_out;

    char* wptr = (char*)d_ws;
    size_t used = 0;
    auto alloc = [&](size_t nbytes) -> void* {
        void* p = wptr + used;
        used += (nbytes + 255) & ~(size_t)255;
        return p;
    };
    float* pbn     = (float*)alloc((size_t)256 * 256 * 4);
    float* ss      = (float*)alloc(256 * 4);
    float* xm      = (float*)alloc((size_t)NB * NCI * 4);
    float* dis     = (float*)alloc((size_t)NB * NN * 4);
    float* selfd   = (float*)alloc((size_t)NB * NN * 4);
    int*   nbr_cnt = (int*)alloc((size_t)NB * NN * 4);
    float* Wt      = (float*)alloc((size_t)ND * NCI * NCO * 4);
    float* y       = (float*)alloc((size_t)NB * NN * NCI * 4);
    float* blog    = (float*)alloc((size_t)NB * NN * ND * 4);
    float* c       = (float*)alloc((size_t)NB * NN * ND * 4);
    float* psum    = (float*)alloc((size_t)NB * 16 * NCI * 4);
    float* pg      = (float*)alloc((size_t)NB * 32 * ND * NCI * 4);
    float* pcs     = (float*)alloc((size_t)NB * 16 * ND * 4);
    float* hbuf    = (float*)alloc((size_t)NB * ND * NCI * 4);
    float* hbb     = (float*)alloc((size_t)NB * ND * 4);
    float* tbuf    = (float*)alloc((size_t)NB * ND * NN * 4);
    int*   nbr_idx = (int*)alloc((size_t)NB * NN * MAXDEG * 4);
    if (used > ws_size) return;

    k_pre1<<<256 + ND, 256, 0, stream>>>(x, pbn, W, Wt);
    k_pre2<<<NB * NN + NB, 256, 0, stream>>>(adj, dis, nbr_idx, nbr_cnt, selfd,
                                             pbn, gamma, beta, ss, xm);
    k_y<<<NB * NN, 128, 0, stream>>>(x, ss, dis, nbr_idx, nbr_cnt, y);

    // iter 0: c uniform (sparsemax of zeros) -> g = rowsum(y)/16, csum = 64
    k_ysum<<<NB * 16, 256, 0, stream>>>(y, psum);
    k_sv<<<NB * ND, 256, 0, stream>>>(psum, psum, W, Wt, bias, xm, hbuf, hbb, out, 0);
    // iter 1
    k_bgc<<<NB * 16, 256, 0, stream>>>(y, hbuf, hbb, blog, c, pg, pcs, 1, 0);
    k_sv<<<NB * ND, 256, 0, stream>>>(pg, pcs, W, Wt, bias, xm, hbuf, hbb, out, 1);
    // iter 2 (final c)
    k_bgc<<<NB * 16, 256, 0, stream>>>(y, hbuf, hbb, blog, c, pg, pcs, 0, 1);
    k_sv<<<NB * ND, 256, 0, stream>>>(pg, pcs, W, Wt, bias, xm, hbuf, hbb, out, 2);

    k_t2<<<NB * NN / 4, 256, 0, stream>>>(c, nbr_idx, nbr_cnt, selfd, tbuf);
    k_adjout<<<NB * ND, 128, 0, stream>>>(tbuf, c, out + (size_t)NB * ND * NCO);
}